// Round 7
// baseline (180.090 us; speedup 1.0000x reference)
//
#include <hip/hip_runtime.h>
#include <math.h>

#define NB 8
#define NF 16384
#define NH 256
#define CL 2                   // steps per chunk
#define CPB (NF / CL)          // 8192 chunks per batch
#define NCHUNK (NB * CPB)      // 65536 chunks
#define NROW (NB * NF)         // 131072 rows
#define SPT (CPB / 256)        // 32 summaries per phaseB thread

#define GZ -9.81007f

// ws layout (floats):
//  rec:   NROW*8      transposed records [i*NCHUNK+c]*8 = ca3, cg3, dt, pad
//  summ:  NCHUNK*12   (P4, T,S,Ux,Uy, Uz,Wx,Wy,Wz)
//  state: NCHUNK*12   (px,py,pz,vx, vy,vz,qw,qx, qy,qz,pad,pad)
//  wp:    NH*16       packed weights: w0..w5, benc, d0..d5, pad3
#define REC_OFF    0
#define SUMM_OFF   ((size_t)NROW * 8)
#define STATE_OFF  (SUMM_OFF + (size_t)NCHUNK * 12)
#define WPACK_OFF  (STATE_OFF + (size_t)NCHUNK * 12)

__device__ __forceinline__ void qrotate(float qw, float qx, float qy, float qz,
                                        float vx, float vy, float vz,
                                        float& ox, float& oy, float& oz) {
    float tx = qy*vz - qz*vy + qw*vx;
    float ty = qz*vx - qx*vz + qw*vy;
    float tz = qx*vy - qy*vx + qw*vz;
    ox = vx + 2.0f*(qy*tz - qz*ty);
    oy = vy + 2.0f*(qz*tx - qx*tz);
    oz = vz + 2.0f*(qx*ty - qy*tx);
}

__device__ __forceinline__ void qmulf(float aw, float ax, float ay, float az,
                                      float bw, float bx, float by, float bz,
                                      float& ow, float& ox, float& oy, float& oz) {
    ow = aw*bw - ax*bx - ay*by - az*bz;
    ox = aw*bx + bw*ax + (ay*bz - az*by);
    oy = aw*by + bw*ay + (az*bx - ax*bz);
    oz = aw*bz + bw*az + (ax*by - ay*bx);
}

// quat_exp(w), |w| <= ~0.03: fp32-exact Taylor of cos(|w|/2), sin(|w|/2)/|w|.
__device__ __forceinline__ void qexpw(float wx, float wy, float wz,
                                      float& ew, float& ex, float& ey, float& ez) {
    float th2 = wx*wx + wy*wy + wz*wz + 1e-16f;
    float h2  = 0.25f * th2;
    ew = 1.0f + h2*(-0.5f + h2*((1.0f/24.0f) - h2*(1.0f/720.0f)));
    float sh = 0.5f + h2*(-(1.0f/12.0f) + h2*(1.0f/240.0f));
    ex = wx*sh; ey = wy*sh; ez = wz*sh;
}

__device__ __forceinline__ float gelu_tanh(float h) {
    float h2 = h*h;
    float u2 = h*(1.5957691216057308f + 0.0713548162726009f*h2);
    float t  = 1.0f - __fdividef(2.0f, 1.0f + __expf(u2));
    float a  = 0.5f*h;
    return a + a*t;
}

struct Sum { float Pw, Px, Py, Pz, T, S, Ux, Uy, Uz, Wx, Wy, Wz; };

__device__ __forceinline__ Sum compose(const Sum& a, const Sum& b) {
    Sum r;
    float RUx, RUy, RUz, RWx, RWy, RWz;
    qrotate(a.Pw, a.Px, a.Py, a.Pz, b.Ux, b.Uy, b.Uz, RUx, RUy, RUz);
    qrotate(a.Pw, a.Px, a.Py, a.Pz, b.Wx, b.Wy, b.Wz, RWx, RWy, RWz);
    r.Ux = a.Ux + RUx;  r.Uy = a.Uy + RUy;  r.Uz = a.Uz + RUz;
    r.Wx = a.Wx + a.Ux*b.T + RWx;
    r.Wy = a.Wy + a.Uy*b.T + RWy;
    r.Wz = a.Wz + a.Uz*b.T + RWz;
    r.S  = a.S + a.T*b.T + b.S;
    r.T  = a.T + b.T;
    float nw, nx, ny, nz;
    qmulf(a.Pw, a.Px, a.Py, a.Pz, b.Pw, b.Px, b.Py, b.Pz, nw, nx, ny, nz);
    float inv = 1.0f / sqrtf(nw*nw + nx*nx + ny*ny + nz*nz);
    r.Pw = nw*inv; r.Px = nx*inv; r.Py = ny*inv; r.Pz = nz*inv;
    return r;
}

__device__ __forceinline__ Sum shflDownSum(const Sum& s, int d) {
    Sum r;
    r.Pw = __shfl_down(s.Pw, d, 64); r.Px = __shfl_down(s.Px, d, 64);
    r.Py = __shfl_down(s.Py, d, 64); r.Pz = __shfl_down(s.Pz, d, 64);
    r.T  = __shfl_down(s.T,  d, 64); r.S  = __shfl_down(s.S,  d, 64);
    r.Ux = __shfl_down(s.Ux, d, 64); r.Uy = __shfl_down(s.Uy, d, 64);
    r.Uz = __shfl_down(s.Uz, d, 64); r.Wx = __shfl_down(s.Wx, d, 64);
    r.Wy = __shfl_down(s.Wy, d, 64); r.Wz = __shfl_down(s.Wz, d, 64);
    return r;
}

struct State { float px, py, pz, vx, vy, vz, qw, qx, qy, qz; };

__device__ __forceinline__ State applySum(const State& st, const Sum& s) {
    State r;
    float RUx, RUy, RUz, RWx, RWy, RWz;
    qrotate(st.qw, st.qx, st.qy, st.qz, s.Ux, s.Uy, s.Uz, RUx, RUy, RUz);
    qrotate(st.qw, st.qx, st.qy, st.qz, s.Wx, s.Wy, s.Wz, RWx, RWy, RWz);
    r.px = st.px + st.vx*s.T + RWx;
    r.py = st.py + st.vy*s.T + RWy;
    r.pz = st.pz + st.vz*s.T + RWz + GZ*s.S;
    r.vx = st.vx + RUx;
    r.vy = st.vy + RUy;
    r.vz = st.vz + RUz + GZ*s.T;
    float nw, nx, ny, nz;
    qmulf(st.qw, st.qx, st.qy, st.qz, s.Pw, s.Px, s.Py, s.Pz, nw, nx, ny, nz);
    float inv = 1.0f / sqrtf(nw*nw + nx*nx + ny*ny + nz*nz);
    r.qw = nw*inv; r.qx = nx*inv; r.qy = ny*inv; r.qz = nz*inv;
    return r;
}

__device__ __forceinline__ Sum loadSum(const float* __restrict__ p, int c) {
    const float* sp = p + (size_t)c*12;
    float4 a0 = ((const float4*)sp)[0];
    float4 a1 = ((const float4*)sp)[1];
    float4 a2 = ((const float4*)sp)[2];
    Sum s;
    s.Pw = a0.x; s.Px = a0.y; s.Py = a0.z; s.Pz = a0.w;
    s.T = a1.x; s.S = a1.y; s.Ux = a1.z; s.Uy = a1.w;
    s.Uz = a2.x; s.Wx = a2.y; s.Wy = a2.z; s.Wz = a2.w;
    return s;
}

// ---- Kernel 0: pack weights into contiguous 64B/hidden-unit records ----
__global__ void repack_kernel(const float* __restrict__ Wenc, const float* __restrict__ benc,
                              const float* __restrict__ Wdec, float* __restrict__ wp) {
    int j = threadIdx.x;
    float* p = wp + j*16;
    p[0] = Wenc[0*NH+j]; p[1] = Wenc[1*NH+j]; p[2] = Wenc[2*NH+j];
    p[3] = Wenc[3*NH+j]; p[4] = Wenc[4*NH+j]; p[5] = Wenc[5*NH+j];
    p[6] = benc[j];
    p[7]  = Wdec[j*6+0]; p[8]  = Wdec[j*6+1]; p[9]  = Wdec[j*6+2];
    p[10] = Wdec[j*6+3]; p[11] = Wdec[j*6+4]; p[12] = Wdec[j*6+5];
    p[13] = 0.0f; p[14] = 0.0f; p[15] = 0.0f;
}

// ---- Kernel 1: MLP + record pack + per-chunk summaries (fused phaseA).
// R4 structure: 64 rows/block (lane -> row), 4 waves split the 256 hidden units;
// weights via ONE contiguous 64B s_load record per j (R4's ~13 scattered s_loads
// were the VALU-idle cause). Epilogue split: wave0 -> out+summ, wave1 -> rec.
__global__ __launch_bounds__(256)
void mlp_summ_kernel(const float* __restrict__ acc, const float* __restrict__ gyro,
                     const float* __restrict__ dtp, const float* __restrict__ wp,
                     const float* __restrict__ bdec,
                     float* __restrict__ out, float* __restrict__ rec,
                     float* __restrict__ summ) {
    __shared__ float part[4][64][8];
    int t = threadIdx.x;
    int lane = t & 63;
    int wv = __builtin_amdgcn_readfirstlane(t >> 6);
    int n = blockIdx.x * 64 + lane;
    float ax = acc[n*3+0], ay = acc[n*3+1], az = acc[n*3+2];
    float gx = gyro[n*3+0], gy = gyro[n*3+1], gz = gyro[n*3+2];
    float c0=0, c1=0, c2=0, c3=0, c4=0, c5=0;
    int j0 = wv * 64;
    #pragma unroll 8
    for (int jj = 0; jj < 64; jj++) {
        const float* w = wp + (j0 + jj)*16;          // uniform -> wide s_load
        float4 wa = *(const float4*)(w);             // w0..w3
        float4 wb = *(const float4*)(w+4);           // w4,w5,benc,d0
        float4 wc = *(const float4*)(w+8);           // d1..d4
        float  wd = w[12];                           // d5
        float h = wb.z + wa.x*ax + wa.y*ay + wa.z*az + wa.w*gx + wb.x*gy + wb.y*gz;
        float g = gelu_tanh(h);
        c0 += g*wb.w; c1 += g*wc.x; c2 += g*wc.y;
        c3 += g*wc.z; c4 += g*wc.w; c5 += g*wd;
    }
    float* pp = part[wv][lane];
    *(float4*)pp     = make_float4(c0, c1, c2, c3);
    *(float2*)(pp+4) = make_float2(c4, c5);
    __syncthreads();

    if (t < 128) {
        int rl = lane;                               // row-local = lane for both waves
        int rn = blockIdx.x * 64 + rl;
        float4 A = *(const float4*)part[0][rl];
        float2 B = *(const float2*)(part[0][rl]+4);
        #pragma unroll
        for (int w = 1; w < 4; w++) {
            float4 A2 = *(const float4*)part[w][rl];
            float2 B2 = *(const float2*)(part[w][rl]+4);
            A.x += A2.x; A.y += A2.y; A.z += A2.z; A.w += A2.w;
            B.x += B2.x; B.y += B2.y;
        }
        float e0 = A.x + bdec[0], e1 = A.y + bdec[1], e2 = A.z + bdec[2];
        float e3 = A.w + bdec[3], e4 = B.x + bdec[4], e5 = B.y + bdec[5];

        if (wv == 1) {
            // wave 1: corrected-record pack (transposed layout for phaseC)
            float dtv = dtp[rn];
            float cax = e0 + acc[rn*3+0], cay = e1 + acc[rn*3+1], caz = e2 + acc[rn*3+2];
            float cgx = e3 + gyro[rn*3+0], cgy = e4 + gyro[rn*3+1], cgz = e5 + gyro[rn*3+2];
            int ci = rn >> 1, ii = rn & 1;           // CL = 2
            float* rp = rec + (size_t)(ii*NCHUNK + ci)*8;
            *(float4*)rp     = make_float4(cax, cay, caz, cgx);
            *(float4*)(rp+4) = make_float4(cgy, cgz, dtv, 0.0f);
        } else {
            // wave 0: correction output + per-chunk summary
            float* ob = out + (size_t)rn*16;
            *(float2*)(ob+10) = make_float2(e0, e1);
            *(float4*)(ob+12) = make_float4(e2, e3, e4, e5);

            float dtv = dtp[rn];
            float cax = e0 + acc[rn*3+0], cay = e1 + acc[rn*3+1], caz = e2 + acc[rn*3+2];
            float cgx = e3 + gyro[rn*3+0], cgy = e4 + gyro[rn*3+1], cgz = e5 + gyro[rn*3+2];
            Sum s;
            float hdt2 = 0.5f*dtv*dtv;
            qexpw(cgx*dtv, cgy*dtv, cgz*dtv, s.Pw, s.Px, s.Py, s.Pz);
            s.T = dtv; s.S = hdt2;
            s.Ux = cax*dtv;  s.Uy = cay*dtv;  s.Uz = caz*dtv;
            s.Wx = cax*hdt2; s.Wy = cay*hdt2; s.Wz = caz*hdt2;
            Sum nb = shflDownSum(s, 1);
            s = compose(s, nb);                      // valid at even lanes
            if ((rl & 1) == 0) {
                float* sp = summ + (size_t)(rn >> 1)*12;
                ((float4*)sp)[0] = make_float4(s.Pw, s.Px, s.Py, s.Pz);
                ((float4*)sp)[1] = make_float4(s.T, s.S, s.Ux, s.Uy);
                ((float4*)sp)[2] = make_float4(s.Uz, s.Wx, s.Wy, s.Wz);
            }
        }
    }
}

// ---- Kernel 2: per-batch parallel scan of 8192 summaries ----
__global__ __launch_bounds__(256)
void phaseB(const float* __restrict__ summ, float* __restrict__ state,
            const float* __restrict__ init_pos, const float* __restrict__ init_vel,
            const float* __restrict__ init_rot) {
    __shared__ float lds[256*12];
    int b = blockIdx.x, t = threadIdx.x;
    int c0 = b*CPB + t*SPT;
    Sum agg = loadSum(summ, c0);
    for (int k = 1; k < SPT; k++) agg = compose(agg, loadSum(summ, c0+k));

    float* mine = lds + t*12;
    mine[0]=agg.Pw; mine[1]=agg.Px; mine[2]=agg.Py; mine[3]=agg.Pz;
    mine[4]=agg.T;  mine[5]=agg.S;  mine[6]=agg.Ux; mine[7]=agg.Uy;
    mine[8]=agg.Uz; mine[9]=agg.Wx; mine[10]=agg.Wy; mine[11]=agg.Wz;
    __syncthreads();
    for (int d = 1; d < 256; d <<= 1) {
        Sum left;
        bool have = (t >= d);
        if (have) {
            const float* lp = lds + (t-d)*12;
            left.Pw=lp[0]; left.Px=lp[1]; left.Py=lp[2]; left.Pz=lp[3];
            left.T=lp[4];  left.S=lp[5];  left.Ux=lp[6]; left.Uy=lp[7];
            left.Uz=lp[8]; left.Wx=lp[9]; left.Wy=lp[10]; left.Wz=lp[11];
        }
        __syncthreads();
        if (have) {
            agg = compose(left, agg);
            mine[0]=agg.Pw; mine[1]=agg.Px; mine[2]=agg.Py; mine[3]=agg.Pz;
            mine[4]=agg.T;  mine[5]=agg.S;  mine[6]=agg.Ux; mine[7]=agg.Uy;
            mine[8]=agg.Uz; mine[9]=agg.Wx; mine[10]=agg.Wy; mine[11]=agg.Wz;
        }
        __syncthreads();
    }
    State st;
    st.px = init_pos[b*3+0]; st.py = init_pos[b*3+1]; st.pz = init_pos[b*3+2];
    st.vx = init_vel[b*3+0]; st.vy = init_vel[b*3+1]; st.vz = init_vel[b*3+2];
    st.qw = init_rot[b*4+0]; st.qx = init_rot[b*4+1]; st.qy = init_rot[b*4+2]; st.qz = init_rot[b*4+3];
    if (t > 0) {
        const float* lp = lds + (t-1)*12;
        Sum pre;
        pre.Pw=lp[0]; pre.Px=lp[1]; pre.Py=lp[2]; pre.Pz=lp[3];
        pre.T=lp[4];  pre.S=lp[5];  pre.Ux=lp[6]; pre.Uy=lp[7];
        pre.Uz=lp[8]; pre.Wx=lp[9]; pre.Wy=lp[10]; pre.Wz=lp[11];
        st = applySum(st, pre);
    }
    for (int k = 0; k < SPT; k++) {
        float* sp = state + (size_t)(c0+k)*12;
        ((float4*)sp)[0] = make_float4(st.px, st.py, st.pz, st.vx);
        ((float4*)sp)[1] = make_float4(st.vy, st.vz, st.qw, st.qx);
        ((float4*)sp)[2] = make_float4(st.qy, st.qz, 0.0f, 0.0f);
        st = applySum(st, loadSum(summ, c0+k));
    }
}

// ---- Kernel 3: replay chunks (2 steps each), direct row writes ----
__global__ __launch_bounds__(256)
void phaseC(const float* __restrict__ rec, const float* __restrict__ state,
            float* __restrict__ out) {
    int c = blockIdx.x * 256 + threadIdx.x;
    const float* sp = state + (size_t)c*12;
    float4 a0 = ((const float4*)sp)[0];
    float4 a1 = ((const float4*)sp)[1];
    float4 a2 = ((const float4*)sp)[2];
    float px = a0.x, py = a0.y, pz = a0.z;
    float vx = a0.w, vy = a1.x, vz = a1.y;
    float qw = a1.z, qx = a1.w, qy = a2.x, qz = a2.y;
    const float4* r = (const float4*)rec;
    float* obase = out + (size_t)c*CL*16;
    #pragma unroll
    for (int i = 0; i < CL; i++) {
        float4 r0 = r[(size_t)(i*NCHUNK + c)*2];
        float4 r1 = r[(size_t)(i*NCHUNK + c)*2 + 1];
        float dtv = r1.z;
        float awx, awy, awz;
        qrotate(qw, qx, qy, qz, r0.x, r0.y, r0.z, awx, awy, awz);
        awz += GZ;
        float hdt2 = 0.5f*dtv*dtv;
        px += vx*dtv + awx*hdt2;
        py += vy*dtv + awy*hdt2;
        pz += vz*dtv + awz*hdt2;
        vx += awx*dtv; vy += awy*dtv; vz += awz*dtv;
        float ew, ex, ey, ez, nw, nx, ny, nz;
        qexpw(r0.w*dtv, r1.x*dtv, r1.y*dtv, ew, ex, ey, ez);
        qmulf(qw, qx, qy, qz, ew, ex, ey, ez, nw, nx, ny, nz);
        float inv = 1.0f / sqrtf(nw*nw + nx*nx + ny*ny + nz*nz);
        qw = nw*inv; qx = nx*inv; qy = ny*inv; qz = nz*inv;
        float* ob = obase + (size_t)i*16;
        *(float4*)(ob+0) = make_float4(px, py, pz, vx);
        *(float4*)(ob+4) = make_float4(vy, vz, qw, qx);
        *(float2*)(ob+8) = make_float2(qy, qz);
    }
}

extern "C" void kernel_launch(void* const* d_in, const int* in_sizes, int n_in,
                              void* d_out, int out_size, void* d_ws, size_t ws_size,
                              hipStream_t stream) {
    const float* acc      = (const float*)d_in[0];
    const float* gyro     = (const float*)d_in[1];
    const float* dt       = (const float*)d_in[2];
    const float* init_pos = (const float*)d_in[3];
    const float* init_vel = (const float*)d_in[4];
    const float* init_rot = (const float*)d_in[5];
    const float* Wenc     = (const float*)d_in[6];
    const float* benc     = (const float*)d_in[7];
    const float* Wdec     = (const float*)d_in[8];
    const float* bdec     = (const float*)d_in[9];
    float* out = (float*)d_out;
    float* ws  = (float*)d_ws;
    float* rec   = ws + REC_OFF;
    float* summ  = ws + SUMM_OFF;
    float* state = ws + STATE_OFF;
    float* wp    = ws + WPACK_OFF;

    repack_kernel<<<1, NH, 0, stream>>>(Wenc, benc, Wdec, wp);
    mlp_summ_kernel<<<NROW/64, 256, 0, stream>>>(acc, gyro, dt, wp, bdec, out, rec, summ);
    phaseB<<<NB, 256, 0, stream>>>(summ, state, init_pos, init_vel, init_rot);
    phaseC<<<NCHUNK/256, 256, 0, stream>>>(rec, state, out);
}

// Round 8
// 142.226 us; speedup vs baseline: 1.2662x; 1.2662x over previous
//
#include <hip/hip_runtime.h>
#include <math.h>

#define NB 8
#define NF 16384
#define NH 256
#define CL 4                   // steps per chunk
#define CPB (NF / CL)          // 4096 chunks per batch
#define NCHUNK (NB * CPB)      // 32768 chunks
#define NROW (NB * NF)         // 131072 rows
#define BT 1024                // phaseB threads per block
#define SPT (CPB / BT)         // 4 summaries per phaseB thread

#define GZ -9.81007f

// ws layout (floats):
//  rec:   NROW*8      transposed records [i*NCHUNK+c]*8 = ca3, cg3, dt, pad
//  summ:  NCHUNK*12   (P4, T,S,Ux,Uy, Uz,Wx,Wy,Wz)
//  state: NCHUNK*12   (px,py,pz,vx, vy,vz,qw,qx, qy,qz,pad,pad)
//  wp:    NH*16       packed weights: w0..w5, benc, d0..d5, pad3
#define REC_OFF    0
#define SUMM_OFF   ((size_t)NROW * 8)
#define STATE_OFF  (SUMM_OFF + (size_t)NCHUNK * 12)
#define WPACK_OFF  (STATE_OFF + (size_t)NCHUNK * 12)

__device__ __forceinline__ void qrotate(float qw, float qx, float qy, float qz,
                                        float vx, float vy, float vz,
                                        float& ox, float& oy, float& oz) {
    float tx = qy*vz - qz*vy + qw*vx;
    float ty = qz*vx - qx*vz + qw*vy;
    float tz = qx*vy - qy*vx + qw*vz;
    ox = vx + 2.0f*(qy*tz - qz*ty);
    oy = vy + 2.0f*(qz*tx - qx*tz);
    oz = vz + 2.0f*(qx*ty - qy*tx);
}

__device__ __forceinline__ void qmulf(float aw, float ax, float ay, float az,
                                      float bw, float bx, float by, float bz,
                                      float& ow, float& ox, float& oy, float& oz) {
    ow = aw*bw - ax*bx - ay*by - az*bz;
    ox = aw*bx + bw*ax + (ay*bz - az*by);
    oy = aw*by + bw*ay + (az*bx - ax*bz);
    oz = aw*bz + bw*az + (ax*by - ay*bx);
}

// quat_exp(w), |w| <= ~0.03: fp32-exact Taylor of cos(|w|/2), sin(|w|/2)/|w|.
__device__ __forceinline__ void qexpw(float wx, float wy, float wz,
                                      float& ew, float& ex, float& ey, float& ez) {
    float th2 = wx*wx + wy*wy + wz*wz + 1e-16f;
    float h2  = 0.25f * th2;
    ew = 1.0f + h2*(-0.5f + h2*((1.0f/24.0f) - h2*(1.0f/720.0f)));
    float sh = 0.5f + h2*(-(1.0f/12.0f) + h2*(1.0f/240.0f));
    ex = wx*sh; ey = wy*sh; ez = wz*sh;
}

__device__ __forceinline__ float gelu_tanh(float h) {
    float h2 = h*h;
    float u2 = h*(1.5957691216057308f + 0.0713548162726009f*h2);
    float t  = 1.0f - __fdividef(2.0f, 1.0f + __expf(u2));
    float a  = 0.5f*h;
    return a + a*t;
}

struct Sum { float Pw, Px, Py, Pz, T, S, Ux, Uy, Uz, Wx, Wy, Wz; };

__device__ __forceinline__ Sum compose(const Sum& a, const Sum& b) {
    Sum r;
    float RUx, RUy, RUz, RWx, RWy, RWz;
    qrotate(a.Pw, a.Px, a.Py, a.Pz, b.Ux, b.Uy, b.Uz, RUx, RUy, RUz);
    qrotate(a.Pw, a.Px, a.Py, a.Pz, b.Wx, b.Wy, b.Wz, RWx, RWy, RWz);
    r.Ux = a.Ux + RUx;  r.Uy = a.Uy + RUy;  r.Uz = a.Uz + RUz;
    r.Wx = a.Wx + a.Ux*b.T + RWx;
    r.Wy = a.Wy + a.Uy*b.T + RWy;
    r.Wz = a.Wz + a.Uz*b.T + RWz;
    r.S  = a.S + a.T*b.T + b.S;
    r.T  = a.T + b.T;
    float nw, nx, ny, nz;
    qmulf(a.Pw, a.Px, a.Py, a.Pz, b.Pw, b.Px, b.Py, b.Pz, nw, nx, ny, nz);
    float inv = 1.0f / sqrtf(nw*nw + nx*nx + ny*ny + nz*nz);
    r.Pw = nw*inv; r.Px = nx*inv; r.Py = ny*inv; r.Pz = nz*inv;
    return r;
}

__device__ __forceinline__ Sum shflDownSum(const Sum& s, int d) {
    Sum r;
    r.Pw = __shfl_down(s.Pw, d, 64); r.Px = __shfl_down(s.Px, d, 64);
    r.Py = __shfl_down(s.Py, d, 64); r.Pz = __shfl_down(s.Pz, d, 64);
    r.T  = __shfl_down(s.T,  d, 64); r.S  = __shfl_down(s.S,  d, 64);
    r.Ux = __shfl_down(s.Ux, d, 64); r.Uy = __shfl_down(s.Uy, d, 64);
    r.Uz = __shfl_down(s.Uz, d, 64); r.Wx = __shfl_down(s.Wx, d, 64);
    r.Wy = __shfl_down(s.Wy, d, 64); r.Wz = __shfl_down(s.Wz, d, 64);
    return r;
}

struct State { float px, py, pz, vx, vy, vz, qw, qx, qy, qz; };

__device__ __forceinline__ State applySum(const State& st, const Sum& s) {
    State r;
    float RUx, RUy, RUz, RWx, RWy, RWz;
    qrotate(st.qw, st.qx, st.qy, st.qz, s.Ux, s.Uy, s.Uz, RUx, RUy, RUz);
    qrotate(st.qw, st.qx, st.qy, st.qz, s.Wx, s.Wy, s.Wz, RWx, RWy, RWz);
    r.px = st.px + st.vx*s.T + RWx;
    r.py = st.py + st.vy*s.T + RWy;
    r.pz = st.pz + st.vz*s.T + RWz + GZ*s.S;
    r.vx = st.vx + RUx;
    r.vy = st.vy + RUy;
    r.vz = st.vz + RUz + GZ*s.T;
    float nw, nx, ny, nz;
    qmulf(st.qw, st.qx, st.qy, st.qz, s.Pw, s.Px, s.Py, s.Pz, nw, nx, ny, nz);
    float inv = 1.0f / sqrtf(nw*nw + nx*nx + ny*ny + nz*nz);
    r.qw = nw*inv; r.qx = nx*inv; r.qy = ny*inv; r.qz = nz*inv;
    return r;
}

__device__ __forceinline__ Sum loadSum(const float* __restrict__ p, int c) {
    const float* sp = p + (size_t)c*12;
    float4 a0 = ((const float4*)sp)[0];
    float4 a1 = ((const float4*)sp)[1];
    float4 a2 = ((const float4*)sp)[2];
    Sum s;
    s.Pw = a0.x; s.Px = a0.y; s.Py = a0.z; s.Pz = a0.w;
    s.T = a1.x; s.S = a1.y; s.Ux = a1.z; s.Uy = a1.w;
    s.Uz = a2.x; s.Wx = a2.y; s.Wy = a2.z; s.Wz = a2.w;
    return s;
}

// ---- Kernel 0: pack weights into contiguous 64B/hidden-unit records ----
__global__ void repack_kernel(const float* __restrict__ Wenc, const float* __restrict__ benc,
                              const float* __restrict__ Wdec, float* __restrict__ wp) {
    int j = threadIdx.x;
    float* p = wp + j*16;
    p[0] = Wenc[0*NH+j]; p[1] = Wenc[1*NH+j]; p[2] = Wenc[2*NH+j];
    p[3] = Wenc[3*NH+j]; p[4] = Wenc[4*NH+j]; p[5] = Wenc[5*NH+j];
    p[6] = benc[j];
    p[7]  = Wdec[j*6+0]; p[8]  = Wdec[j*6+1]; p[9]  = Wdec[j*6+2];
    p[10] = Wdec[j*6+3]; p[11] = Wdec[j*6+4]; p[12] = Wdec[j*6+5];
    p[13] = 0.0f; p[14] = 0.0f; p[15] = 0.0f;
}

// ---- Kernel 1: MLP + record pack + per-chunk summaries (fused phaseA).
// 64 rows/block (lane -> row), 4 waves split the 256 hidden units; weights via
// ONE contiguous 64B record per j (4 wide s_loads). Epilogue: wave0 -> out+summ,
// wave1 -> rec (both re-reduce from LDS).
__global__ __launch_bounds__(256)
void mlp_summ_kernel(const float* __restrict__ acc, const float* __restrict__ gyro,
                     const float* __restrict__ dtp, const float* __restrict__ wp,
                     const float* __restrict__ bdec,
                     float* __restrict__ out, float* __restrict__ rec,
                     float* __restrict__ summ) {
    __shared__ float part[4][64][8];
    int t = threadIdx.x;
    int lane = t & 63;
    int wv = __builtin_amdgcn_readfirstlane(t >> 6);
    int n = blockIdx.x * 64 + lane;
    float ax = acc[n*3+0], ay = acc[n*3+1], az = acc[n*3+2];
    float gx = gyro[n*3+0], gy = gyro[n*3+1], gz = gyro[n*3+2];
    float c0=0, c1=0, c2=0, c3=0, c4=0, c5=0;
    int j0 = wv * 64;
    #pragma unroll 8
    for (int jj = 0; jj < 64; jj++) {
        const float* w = wp + (j0 + jj)*16;          // uniform -> wide s_load
        float4 wa = *(const float4*)(w);             // w0..w3
        float4 wb = *(const float4*)(w+4);           // w4,w5,benc,d0
        float4 wc = *(const float4*)(w+8);           // d1..d4
        float  wd = w[12];                           // d5
        float h = wb.z + wa.x*ax + wa.y*ay + wa.z*az + wa.w*gx + wb.x*gy + wb.y*gz;
        float g = gelu_tanh(h);
        c0 += g*wb.w; c1 += g*wc.x; c2 += g*wc.y;
        c3 += g*wc.z; c4 += g*wc.w; c5 += g*wd;
    }
    float* pp = part[wv][lane];
    *(float4*)pp     = make_float4(c0, c1, c2, c3);
    *(float2*)(pp+4) = make_float2(c4, c5);
    __syncthreads();

    if (t < 128) {
        int rl = lane;
        int rn = blockIdx.x * 64 + rl;
        float4 A = *(const float4*)part[0][rl];
        float2 B = *(const float2*)(part[0][rl]+4);
        #pragma unroll
        for (int w = 1; w < 4; w++) {
            float4 A2 = *(const float4*)part[w][rl];
            float2 B2 = *(const float2*)(part[w][rl]+4);
            A.x += A2.x; A.y += A2.y; A.z += A2.z; A.w += A2.w;
            B.x += B2.x; B.y += B2.y;
        }
        float e0 = A.x + bdec[0], e1 = A.y + bdec[1], e2 = A.z + bdec[2];
        float e3 = A.w + bdec[3], e4 = B.x + bdec[4], e5 = B.y + bdec[5];
        float dtv = dtp[rn];
        float cax = e0 + acc[rn*3+0], cay = e1 + acc[rn*3+1], caz = e2 + acc[rn*3+2];
        float cgx = e3 + gyro[rn*3+0], cgy = e4 + gyro[rn*3+1], cgz = e5 + gyro[rn*3+2];

        if (wv == 1) {
            // wave 1: corrected-record pack (transposed layout for phaseC)
            int ci = rn >> 2, ii = rn & 3;           // CL = 4
            float* rp = rec + (size_t)(ii*NCHUNK + ci)*8;
            *(float4*)rp     = make_float4(cax, cay, caz, cgx);
            *(float4*)(rp+4) = make_float4(cgy, cgz, dtv, 0.0f);
        } else {
            // wave 0: correction output + per-chunk summary
            float* ob = out + (size_t)rn*16;
            *(float2*)(ob+10) = make_float2(e0, e1);
            *(float4*)(ob+12) = make_float4(e2, e3, e4, e5);

            Sum s;
            float hdt2 = 0.5f*dtv*dtv;
            qexpw(cgx*dtv, cgy*dtv, cgz*dtv, s.Pw, s.Px, s.Py, s.Pz);
            s.T = dtv; s.S = hdt2;
            s.Ux = cax*dtv;  s.Uy = cay*dtv;  s.Uz = caz*dtv;
            s.Wx = cax*hdt2; s.Wy = cay*hdt2; s.Wz = caz*hdt2;
            Sum nb = shflDownSum(s, 1);
            s = compose(s, nb);                      // valid at even lanes
            nb = shflDownSum(s, 2);
            s = compose(s, nb);                      // valid at lane%4==0
            if ((rl & 3) == 0) {
                float* sp = summ + (size_t)(rn >> 2)*12;
                ((float4*)sp)[0] = make_float4(s.Pw, s.Px, s.Py, s.Pz);
                ((float4*)sp)[1] = make_float4(s.T, s.S, s.Ux, s.Uy);
                ((float4*)sp)[2] = make_float4(s.Uz, s.Wx, s.Wy, s.Wz);
            }
        }
    }
}

// ---- Kernel 2: per-batch parallel scan, 1024 threads (SPT=4, short chains) ----
__global__ __launch_bounds__(1024)
void phaseB(const float* __restrict__ summ, float* __restrict__ state,
            const float* __restrict__ init_pos, const float* __restrict__ init_vel,
            const float* __restrict__ init_rot) {
    __shared__ float lds[BT*12];                    // 48 KB
    int b = blockIdx.x, t = threadIdx.x;
    int c0 = b*CPB + t*SPT;
    Sum s[SPT];
    #pragma unroll
    for (int k = 0; k < SPT; k++) s[k] = loadSum(summ, c0+k);
    Sum agg = s[0];
    #pragma unroll
    for (int k = 1; k < SPT; k++) agg = compose(agg, s[k]);

    float* mine = lds + t*12;
    mine[0]=agg.Pw; mine[1]=agg.Px; mine[2]=agg.Py; mine[3]=agg.Pz;
    mine[4]=agg.T;  mine[5]=agg.S;  mine[6]=agg.Ux; mine[7]=agg.Uy;
    mine[8]=agg.Uz; mine[9]=agg.Wx; mine[10]=agg.Wy; mine[11]=agg.Wz;
    __syncthreads();
    for (int d = 1; d < BT; d <<= 1) {
        Sum left;
        bool have = (t >= d);
        if (have) {
            const float* lp = lds + (t-d)*12;
            left.Pw=lp[0]; left.Px=lp[1]; left.Py=lp[2]; left.Pz=lp[3];
            left.T=lp[4];  left.S=lp[5];  left.Ux=lp[6]; left.Uy=lp[7];
            left.Uz=lp[8]; left.Wx=lp[9]; left.Wy=lp[10]; left.Wz=lp[11];
        }
        __syncthreads();
        if (have) {
            agg = compose(left, agg);
            mine[0]=agg.Pw; mine[1]=agg.Px; mine[2]=agg.Py; mine[3]=agg.Pz;
            mine[4]=agg.T;  mine[5]=agg.S;  mine[6]=agg.Ux; mine[7]=agg.Uy;
            mine[8]=agg.Uz; mine[9]=agg.Wx; mine[10]=agg.Wy; mine[11]=agg.Wz;
        }
        __syncthreads();
    }
    State st;
    st.px = init_pos[b*3+0]; st.py = init_pos[b*3+1]; st.pz = init_pos[b*3+2];
    st.vx = init_vel[b*3+0]; st.vy = init_vel[b*3+1]; st.vz = init_vel[b*3+2];
    st.qw = init_rot[b*4+0]; st.qx = init_rot[b*4+1]; st.qy = init_rot[b*4+2]; st.qz = init_rot[b*4+3];
    if (t > 0) {
        const float* lp = lds + (t-1)*12;
        Sum pre;
        pre.Pw=lp[0]; pre.Px=lp[1]; pre.Py=lp[2]; pre.Pz=lp[3];
        pre.T=lp[4];  pre.S=lp[5];  pre.Ux=lp[6]; pre.Uy=lp[7];
        pre.Uz=lp[8]; pre.Wx=lp[9]; pre.Wy=lp[10]; pre.Wz=lp[11];
        st = applySum(st, pre);
    }
    #pragma unroll
    for (int k = 0; k < SPT; k++) {
        float* sp = state + (size_t)(c0+k)*12;
        ((float4*)sp)[0] = make_float4(st.px, st.py, st.pz, st.vx);
        ((float4*)sp)[1] = make_float4(st.vy, st.vz, st.qw, st.qx);
        ((float4*)sp)[2] = make_float4(st.qy, st.qz, 0.0f, 0.0f);
        st = applySum(st, s[k]);
    }
}

// ---- Kernel 3: replay chunks (4 steps each), direct row writes ----
__global__ __launch_bounds__(256)
void phaseC(const float* __restrict__ rec, const float* __restrict__ state,
            float* __restrict__ out) {
    int c = blockIdx.x * 256 + threadIdx.x;
    const float* sp = state + (size_t)c*12;
    float4 a0 = ((const float4*)sp)[0];
    float4 a1 = ((const float4*)sp)[1];
    float4 a2 = ((const float4*)sp)[2];
    float px = a0.x, py = a0.y, pz = a0.z;
    float vx = a0.w, vy = a1.x, vz = a1.y;
    float qw = a1.z, qx = a1.w, qy = a2.x, qz = a2.y;
    const float4* r = (const float4*)rec;
    float* obase = out + (size_t)c*CL*16;
    #pragma unroll
    for (int i = 0; i < CL; i++) {
        float4 r0 = r[(size_t)(i*NCHUNK + c)*2];
        float4 r1 = r[(size_t)(i*NCHUNK + c)*2 + 1];
        float dtv = r1.z;
        float awx, awy, awz;
        qrotate(qw, qx, qy, qz, r0.x, r0.y, r0.z, awx, awy, awz);
        awz += GZ;
        float hdt2 = 0.5f*dtv*dtv;
        px += vx*dtv + awx*hdt2;
        py += vy*dtv + awy*hdt2;
        pz += vz*dtv + awz*hdt2;
        vx += awx*dtv; vy += awy*dtv; vz += awz*dtv;
        float ew, ex, ey, ez, nw, nx, ny, nz;
        qexpw(r0.w*dtv, r1.x*dtv, r1.y*dtv, ew, ex, ey, ez);
        qmulf(qw, qx, qy, qz, ew, ex, ey, ez, nw, nx, ny, nz);
        float inv = 1.0f / sqrtf(nw*nw + nx*nx + ny*ny + nz*nz);
        qw = nw*inv; qx = nx*inv; qy = ny*inv; qz = nz*inv;
        float* ob = obase + (size_t)i*16;
        *(float4*)(ob+0) = make_float4(px, py, pz, vx);
        *(float4*)(ob+4) = make_float4(vy, vz, qw, qx);
        *(float2*)(ob+8) = make_float2(qy, qz);
    }
}

extern "C" void kernel_launch(void* const* d_in, const int* in_sizes, int n_in,
                              void* d_out, int out_size, void* d_ws, size_t ws_size,
                              hipStream_t stream) {
    const float* acc      = (const float*)d_in[0];
    const float* gyro     = (const float*)d_in[1];
    const float* dt       = (const float*)d_in[2];
    const float* init_pos = (const float*)d_in[3];
    const float* init_vel = (const float*)d_in[4];
    const float* init_rot = (const float*)d_in[5];
    const float* Wenc     = (const float*)d_in[6];
    const float* benc     = (const float*)d_in[7];
    const float* Wdec     = (const float*)d_in[8];
    const float* bdec     = (const float*)d_in[9];
    float* out = (float*)d_out;
    float* ws  = (float*)d_ws;
    float* rec   = ws + REC_OFF;
    float* summ  = ws + SUMM_OFF;
    float* state = ws + STATE_OFF;
    float* wp    = ws + WPACK_OFF;

    repack_kernel<<<1, NH, 0, stream>>>(Wenc, benc, Wdec, wp);
    mlp_summ_kernel<<<NROW/64, 256, 0, stream>>>(acc, gyro, dt, wp, bdec, out, rec, summ);
    phaseB<<<NB, BT, 0, stream>>>(summ, state, init_pos, init_vel, init_rot);
    phaseC<<<NCHUNK/256, 256, 0, stream>>>(rec, state, out);
}

// Round 9
// 128.931 us; speedup vs baseline: 1.3968x; 1.1031x over previous
//
#include <hip/hip_runtime.h>
#include <math.h>

#define NB 8
#define NF 16384
#define NH 256
#define CL 4                   // steps per chunk
#define CPB (NF / CL)          // 4096 chunks per batch
#define NCHUNK (NB * CPB)      // 32768 chunks
#define NROW (NB * NF)         // 131072 rows
#define SBLK (NCHUNK / 256)    // 128 scan blocks (16 per batch)
#define BPB (CPB / 256)        // 16 scan blocks per batch

#define GZ -9.81007f

// ws layout (floats):
//  rec:    NROW*8     transposed records [i*NCHUNK+c]*8 = ca3, cg3, dt, pad
//  summ:   NCHUNK*12  per-chunk summaries
//  pref:   NCHUNK*12  in-block inclusive prefix summaries
//  wp:     NH*16      packed weights: w0..w5, benc, d0..d5, pad3
//  bsum:   SBLK*12    per-scan-block total summaries
//  bstate: SBLK*12    per-scan-block start states
#define REC_OFF    0
#define SUMM_OFF   ((size_t)NROW * 8)
#define PREF_OFF   (SUMM_OFF + (size_t)NCHUNK * 12)
#define WPACK_OFF  (PREF_OFF + (size_t)NCHUNK * 12)
#define BSUM_OFF   (WPACK_OFF + (size_t)NH * 16)
#define BSTATE_OFF (BSUM_OFF + (size_t)SBLK * 12)

__device__ __forceinline__ void qrotate(float qw, float qx, float qy, float qz,
                                        float vx, float vy, float vz,
                                        float& ox, float& oy, float& oz) {
    float tx = qy*vz - qz*vy + qw*vx;
    float ty = qz*vx - qx*vz + qw*vy;
    float tz = qx*vy - qy*vx + qw*vz;
    ox = vx + 2.0f*(qy*tz - qz*ty);
    oy = vy + 2.0f*(qz*tx - qx*tz);
    oz = vz + 2.0f*(qx*ty - qy*tx);
}

__device__ __forceinline__ void qmulf(float aw, float ax, float ay, float az,
                                      float bw, float bx, float by, float bz,
                                      float& ow, float& ox, float& oy, float& oz) {
    ow = aw*bw - ax*bx - ay*by - az*bz;
    ox = aw*bx + bw*ax + (ay*bz - az*by);
    oy = aw*by + bw*ay + (az*bx - ax*bz);
    oz = aw*bz + bw*az + (ax*by - ay*bx);
}

// quat_exp(w), |w| <= ~0.03: fp32-exact Taylor of cos(|w|/2), sin(|w|/2)/|w|.
__device__ __forceinline__ void qexpw(float wx, float wy, float wz,
                                      float& ew, float& ex, float& ey, float& ez) {
    float th2 = wx*wx + wy*wy + wz*wz + 1e-16f;
    float h2  = 0.25f * th2;
    ew = 1.0f + h2*(-0.5f + h2*((1.0f/24.0f) - h2*(1.0f/720.0f)));
    float sh = 0.5f + h2*(-(1.0f/12.0f) + h2*(1.0f/240.0f));
    ex = wx*sh; ey = wy*sh; ez = wz*sh;
}

__device__ __forceinline__ float gelu_tanh(float h) {
    float h2 = h*h;
    float u2 = h*(1.5957691216057308f + 0.0713548162726009f*h2);
    float t  = 1.0f - __fdividef(2.0f, 1.0f + __expf(u2));
    float a  = 0.5f*h;
    return a + a*t;
}

struct Sum { float Pw, Px, Py, Pz, T, S, Ux, Uy, Uz, Wx, Wy, Wz; };

__device__ __forceinline__ Sum compose(const Sum& a, const Sum& b) {
    Sum r;
    float RUx, RUy, RUz, RWx, RWy, RWz;
    qrotate(a.Pw, a.Px, a.Py, a.Pz, b.Ux, b.Uy, b.Uz, RUx, RUy, RUz);
    qrotate(a.Pw, a.Px, a.Py, a.Pz, b.Wx, b.Wy, b.Wz, RWx, RWy, RWz);
    r.Ux = a.Ux + RUx;  r.Uy = a.Uy + RUy;  r.Uz = a.Uz + RUz;
    r.Wx = a.Wx + a.Ux*b.T + RWx;
    r.Wy = a.Wy + a.Uy*b.T + RWy;
    r.Wz = a.Wz + a.Uz*b.T + RWz;
    r.S  = a.S + a.T*b.T + b.S;
    r.T  = a.T + b.T;
    float nw, nx, ny, nz;
    qmulf(a.Pw, a.Px, a.Py, a.Pz, b.Pw, b.Px, b.Py, b.Pz, nw, nx, ny, nz);
    float inv = 1.0f / sqrtf(nw*nw + nx*nx + ny*ny + nz*nz);
    r.Pw = nw*inv; r.Px = nx*inv; r.Py = ny*inv; r.Pz = nz*inv;
    return r;
}

__device__ __forceinline__ Sum shflDownSum(const Sum& s, int d) {
    Sum r;
    r.Pw = __shfl_down(s.Pw, d, 64); r.Px = __shfl_down(s.Px, d, 64);
    r.Py = __shfl_down(s.Py, d, 64); r.Pz = __shfl_down(s.Pz, d, 64);
    r.T  = __shfl_down(s.T,  d, 64); r.S  = __shfl_down(s.S,  d, 64);
    r.Ux = __shfl_down(s.Ux, d, 64); r.Uy = __shfl_down(s.Uy, d, 64);
    r.Uz = __shfl_down(s.Uz, d, 64); r.Wx = __shfl_down(s.Wx, d, 64);
    r.Wy = __shfl_down(s.Wy, d, 64); r.Wz = __shfl_down(s.Wz, d, 64);
    return r;
}

struct State { float px, py, pz, vx, vy, vz, qw, qx, qy, qz; };

__device__ __forceinline__ State applySum(const State& st, const Sum& s) {
    State r;
    float RUx, RUy, RUz, RWx, RWy, RWz;
    qrotate(st.qw, st.qx, st.qy, st.qz, s.Ux, s.Uy, s.Uz, RUx, RUy, RUz);
    qrotate(st.qw, st.qx, st.qy, st.qz, s.Wx, s.Wy, s.Wz, RWx, RWy, RWz);
    r.px = st.px + st.vx*s.T + RWx;
    r.py = st.py + st.vy*s.T + RWy;
    r.pz = st.pz + st.vz*s.T + RWz + GZ*s.S;
    r.vx = st.vx + RUx;
    r.vy = st.vy + RUy;
    r.vz = st.vz + RUz + GZ*s.T;
    float nw, nx, ny, nz;
    qmulf(st.qw, st.qx, st.qy, st.qz, s.Pw, s.Px, s.Py, s.Pz, nw, nx, ny, nz);
    float inv = 1.0f / sqrtf(nw*nw + nx*nx + ny*ny + nz*nz);
    r.qw = nw*inv; r.qx = nx*inv; r.qy = ny*inv; r.qz = nz*inv;
    return r;
}

__device__ __forceinline__ Sum loadSum(const float* __restrict__ p, int c) {
    const float* sp = p + (size_t)c*12;
    float4 a0 = ((const float4*)sp)[0];
    float4 a1 = ((const float4*)sp)[1];
    float4 a2 = ((const float4*)sp)[2];
    Sum s;
    s.Pw = a0.x; s.Px = a0.y; s.Py = a0.z; s.Pz = a0.w;
    s.T = a1.x; s.S = a1.y; s.Ux = a1.z; s.Uy = a1.w;
    s.Uz = a2.x; s.Wx = a2.y; s.Wy = a2.z; s.Wz = a2.w;
    return s;
}

__device__ __forceinline__ void storeSum(float* __restrict__ sp, const Sum& s) {
    ((float4*)sp)[0] = make_float4(s.Pw, s.Px, s.Py, s.Pz);
    ((float4*)sp)[1] = make_float4(s.T, s.S, s.Ux, s.Uy);
    ((float4*)sp)[2] = make_float4(s.Uz, s.Wx, s.Wy, s.Wz);
}

// ---- Kernel 0: pack weights into contiguous 64B/hidden-unit records ----
__global__ void repack_kernel(const float* __restrict__ Wenc, const float* __restrict__ benc,
                              const float* __restrict__ Wdec, float* __restrict__ wp) {
    int j = threadIdx.x;
    float* p = wp + j*16;
    p[0] = Wenc[0*NH+j]; p[1] = Wenc[1*NH+j]; p[2] = Wenc[2*NH+j];
    p[3] = Wenc[3*NH+j]; p[4] = Wenc[4*NH+j]; p[5] = Wenc[5*NH+j];
    p[6] = benc[j];
    p[7]  = Wdec[j*6+0]; p[8]  = Wdec[j*6+1]; p[9]  = Wdec[j*6+2];
    p[10] = Wdec[j*6+3]; p[11] = Wdec[j*6+4]; p[12] = Wdec[j*6+5];
    p[13] = 0.0f; p[14] = 0.0f; p[15] = 0.0f;
}

// ---- Kernel 1: MLP + record pack + per-chunk summaries.
// 64 rows/block (lane -> row), 4 waves split the 256 hidden units; weights via
// one contiguous 64B record per j. Epilogue spread over 3 waves:
// wave0 -> summaries, wave1 -> rec pack, wave2 -> out correction.
__global__ __launch_bounds__(256)
void mlp_summ_kernel(const float* __restrict__ acc, const float* __restrict__ gyro,
                     const float* __restrict__ dtp, const float* __restrict__ wp,
                     const float* __restrict__ bdec,
                     float* __restrict__ out, float* __restrict__ rec,
                     float* __restrict__ summ) {
    __shared__ float part[4][64][8];
    int t = threadIdx.x;
    int lane = t & 63;
    int wv = __builtin_amdgcn_readfirstlane(t >> 6);
    int n = blockIdx.x * 64 + lane;
    float ax = acc[n*3+0], ay = acc[n*3+1], az = acc[n*3+2];
    float gx = gyro[n*3+0], gy = gyro[n*3+1], gz = gyro[n*3+2];
    float c0=0, c1=0, c2=0, c3=0, c4=0, c5=0;
    int j0 = wv * 64;
    #pragma unroll 8
    for (int jj = 0; jj < 64; jj++) {
        const float* w = wp + (j0 + jj)*16;          // uniform -> wide s_load
        float4 wa = *(const float4*)(w);             // w0..w3
        float4 wb = *(const float4*)(w+4);           // w4,w5,benc,d0
        float4 wc = *(const float4*)(w+8);           // d1..d4
        float  wd = w[12];                           // d5
        float h = wb.z + wa.x*ax + wa.y*ay + wa.z*az + wa.w*gx + wb.x*gy + wb.y*gz;
        float g = gelu_tanh(h);
        c0 += g*wb.w; c1 += g*wc.x; c2 += g*wc.y;
        c3 += g*wc.z; c4 += g*wc.w; c5 += g*wd;
    }
    float* pp = part[wv][lane];
    *(float4*)pp     = make_float4(c0, c1, c2, c3);
    *(float2*)(pp+4) = make_float2(c4, c5);
    __syncthreads();

    if (wv < 3) {
        int rl = lane;
        int rn = blockIdx.x * 64 + rl;
        float4 A = *(const float4*)part[0][rl];
        float2 B = *(const float2*)(part[0][rl]+4);
        #pragma unroll
        for (int w = 1; w < 4; w++) {
            float4 A2 = *(const float4*)part[w][rl];
            float2 B2 = *(const float2*)(part[w][rl]+4);
            A.x += A2.x; A.y += A2.y; A.z += A2.z; A.w += A2.w;
            B.x += B2.x; B.y += B2.y;
        }
        float e0 = A.x + bdec[0], e1 = A.y + bdec[1], e2 = A.z + bdec[2];
        float e3 = A.w + bdec[3], e4 = B.x + bdec[4], e5 = B.y + bdec[5];

        if (wv == 2) {
            // wave 2: correction output
            float* ob = out + (size_t)rn*16;
            *(float2*)(ob+10) = make_float2(e0, e1);
            *(float4*)(ob+12) = make_float4(e2, e3, e4, e5);
        } else {
            float dtv = dtp[rn];
            float cax = e0 + acc[rn*3+0], cay = e1 + acc[rn*3+1], caz = e2 + acc[rn*3+2];
            float cgx = e3 + gyro[rn*3+0], cgy = e4 + gyro[rn*3+1], cgz = e5 + gyro[rn*3+2];
            if (wv == 1) {
                // wave 1: corrected-record pack (transposed layout for phaseC)
                int ci = rn >> 2, ii = rn & 3;       // CL = 4
                float* rp = rec + (size_t)(ii*NCHUNK + ci)*8;
                *(float4*)rp     = make_float4(cax, cay, caz, cgx);
                *(float4*)(rp+4) = make_float4(cgy, cgz, dtv, 0.0f);
            } else {
                // wave 0: per-chunk summary (tree-compose 4 consecutive lanes)
                Sum s;
                float hdt2 = 0.5f*dtv*dtv;
                qexpw(cgx*dtv, cgy*dtv, cgz*dtv, s.Pw, s.Px, s.Py, s.Pz);
                s.T = dtv; s.S = hdt2;
                s.Ux = cax*dtv;  s.Uy = cay*dtv;  s.Uz = caz*dtv;
                s.Wx = cax*hdt2; s.Wy = cay*hdt2; s.Wz = caz*hdt2;
                Sum nb = shflDownSum(s, 1);
                s = compose(s, nb);                  // valid at even lanes
                nb = shflDownSum(s, 2);
                s = compose(s, nb);                  // valid at lane%4==0
                if ((rl & 3) == 0) storeSum(summ + (size_t)(rn >> 2)*12, s);
            }
        }
    }
}

// ---- Kernel 2: in-block inclusive scan (one thread per chunk, 8 LDS rounds) ----
__global__ __launch_bounds__(256)
void scan1(const float* __restrict__ summ, float* __restrict__ pref,
           float* __restrict__ bsum) {
    __shared__ float lds[256*13];                   // stride 13: conflict-free
    int t = threadIdx.x;
    int c = blockIdx.x * 256 + t;
    Sum agg = loadSum(summ, c);
    float* mine = lds + t*13;
    mine[0]=agg.Pw; mine[1]=agg.Px; mine[2]=agg.Py; mine[3]=agg.Pz;
    mine[4]=agg.T;  mine[5]=agg.S;  mine[6]=agg.Ux; mine[7]=agg.Uy;
    mine[8]=agg.Uz; mine[9]=agg.Wx; mine[10]=agg.Wy; mine[11]=agg.Wz;
    __syncthreads();
    for (int d = 1; d < 256; d <<= 1) {
        Sum left;
        bool have = (t >= d);
        if (have) {
            const float* lp = lds + (t-d)*13;
            left.Pw=lp[0]; left.Px=lp[1]; left.Py=lp[2]; left.Pz=lp[3];
            left.T=lp[4];  left.S=lp[5];  left.Ux=lp[6]; left.Uy=lp[7];
            left.Uz=lp[8]; left.Wx=lp[9]; left.Wy=lp[10]; left.Wz=lp[11];
        }
        __syncthreads();
        if (have) {
            agg = compose(left, agg);
            mine[0]=agg.Pw; mine[1]=agg.Px; mine[2]=agg.Py; mine[3]=agg.Pz;
            mine[4]=agg.T;  mine[5]=agg.S;  mine[6]=agg.Ux; mine[7]=agg.Uy;
            mine[8]=agg.Uz; mine[9]=agg.Wx; mine[10]=agg.Wy; mine[11]=agg.Wz;
        }
        __syncthreads();
    }
    storeSum(pref + (size_t)c*12, agg);
    if (t == 255) storeSum(bsum + (size_t)blockIdx.x*12, agg);
}

// ---- Kernel 3: per-batch serial combine of 16 block totals -> block states ----
__global__ void scan2(const float* __restrict__ bsum, float* __restrict__ bstate,
                      const float* __restrict__ init_pos, const float* __restrict__ init_vel,
                      const float* __restrict__ init_rot) {
    int b = threadIdx.x;
    if (b >= NB) return;
    State st;
    st.px = init_pos[b*3+0]; st.py = init_pos[b*3+1]; st.pz = init_pos[b*3+2];
    st.vx = init_vel[b*3+0]; st.vy = init_vel[b*3+1]; st.vz = init_vel[b*3+2];
    st.qw = init_rot[b*4+0]; st.qx = init_rot[b*4+1]; st.qy = init_rot[b*4+2]; st.qz = init_rot[b*4+3];
    for (int k = 0; k < BPB; k++) {
        int bb = b*BPB + k;
        float* sp = bstate + (size_t)bb*12;
        ((float4*)sp)[0] = make_float4(st.px, st.py, st.pz, st.vx);
        ((float4*)sp)[1] = make_float4(st.vy, st.vz, st.qw, st.qx);
        ((float4*)sp)[2] = make_float4(st.qy, st.qz, 0.0f, 0.0f);
        st = applySum(st, loadSum(bsum, bb));
    }
}

// ---- Kernel 4: chunk-start state = bstate o pref[c-1]; replay 4 steps ----
__global__ __launch_bounds__(256)
void phaseC(const float* __restrict__ rec, const float* __restrict__ pref,
            const float* __restrict__ bstate, float* __restrict__ out) {
    int t = threadIdx.x;
    int c = blockIdx.x * 256 + t;
    const float* bp = bstate + (size_t)blockIdx.x*12;
    float4 a0 = ((const float4*)bp)[0];
    float4 a1 = ((const float4*)bp)[1];
    float4 a2 = ((const float4*)bp)[2];
    State st;
    st.px = a0.x; st.py = a0.y; st.pz = a0.z;
    st.vx = a0.w; st.vy = a1.x; st.vz = a1.y;
    st.qw = a1.z; st.qx = a1.w; st.qy = a2.x; st.qz = a2.y;
    if (t > 0) st = applySum(st, loadSum(pref, c-1));
    float px = st.px, py = st.py, pz = st.pz;
    float vx = st.vx, vy = st.vy, vz = st.vz;
    float qw = st.qw, qx = st.qx, qy = st.qy, qz = st.qz;
    const float4* r = (const float4*)rec;
    float* obase = out + (size_t)c*CL*16;
    #pragma unroll
    for (int i = 0; i < CL; i++) {
        float4 r0 = r[(size_t)(i*NCHUNK + c)*2];
        float4 r1 = r[(size_t)(i*NCHUNK + c)*2 + 1];
        float dtv = r1.z;
        float awx, awy, awz;
        qrotate(qw, qx, qy, qz, r0.x, r0.y, r0.z, awx, awy, awz);
        awz += GZ;
        float hdt2 = 0.5f*dtv*dtv;
        px += vx*dtv + awx*hdt2;
        py += vy*dtv + awy*hdt2;
        pz += vz*dtv + awz*hdt2;
        vx += awx*dtv; vy += awy*dtv; vz += awz*dtv;
        float ew, ex, ey, ez, nw, nx, ny, nz;
        qexpw(r0.w*dtv, r1.x*dtv, r1.y*dtv, ew, ex, ey, ez);
        qmulf(qw, qx, qy, qz, ew, ex, ey, ez, nw, nx, ny, nz);
        float inv = 1.0f / sqrtf(nw*nw + nx*nx + ny*ny + nz*nz);
        qw = nw*inv; qx = nx*inv; qy = ny*inv; qz = nz*inv;
        float* ob = obase + (size_t)i*16;
        *(float4*)(ob+0) = make_float4(px, py, pz, vx);
        *(float4*)(ob+4) = make_float4(vy, vz, qw, qx);
        *(float2*)(ob+8) = make_float2(qy, qz);
    }
}

extern "C" void kernel_launch(void* const* d_in, const int* in_sizes, int n_in,
                              void* d_out, int out_size, void* d_ws, size_t ws_size,
                              hipStream_t stream) {
    const float* acc      = (const float*)d_in[0];
    const float* gyro     = (const float*)d_in[1];
    const float* dt       = (const float*)d_in[2];
    const float* init_pos = (const float*)d_in[3];
    const float* init_vel = (const float*)d_in[4];
    const float* init_rot = (const float*)d_in[5];
    const float* Wenc     = (const float*)d_in[6];
    const float* benc     = (const float*)d_in[7];
    const float* Wdec     = (const float*)d_in[8];
    const float* bdec     = (const float*)d_in[9];
    float* out = (float*)d_out;
    float* ws  = (float*)d_ws;
    float* rec    = ws + REC_OFF;
    float* summ   = ws + SUMM_OFF;
    float* pref   = ws + PREF_OFF;
    float* wp     = ws + WPACK_OFF;
    float* bsum   = ws + BSUM_OFF;
    float* bstate = ws + BSTATE_OFF;

    repack_kernel<<<1, NH, 0, stream>>>(Wenc, benc, Wdec, wp);
    mlp_summ_kernel<<<NROW/64, 256, 0, stream>>>(acc, gyro, dt, wp, bdec, out, rec, summ);
    scan1<<<SBLK, 256, 0, stream>>>(summ, pref, bsum);
    scan2<<<1, 64, 0, stream>>>(bsum, bstate, init_pos, init_vel, init_rot);
    phaseC<<<SBLK, 256, 0, stream>>>(rec, pref, bstate, out);
}

// Round 10
// 127.663 us; speedup vs baseline: 1.4107x; 1.0099x over previous
//
#include <hip/hip_runtime.h>
#include <math.h>

#define NB 8
#define NF 16384
#define NH 256
#define CL 4                   // steps per chunk
#define CPB (NF / CL)          // 4096 chunks per batch
#define NCHUNK (NB * CPB)      // 32768 chunks
#define NROW (NB * NF)         // 131072 rows
#define SBLK (NCHUNK / 256)    // 128 scan blocks (16 per batch)
#define BPB (CPB / 256)        // 16 scan blocks per batch

#define GZ -9.81007f

// ws layout (floats):
//  rec:    NROW*8     transposed records [i*NCHUNK+c]*8 = ca3, cg3, dt, pad
//  summ:   NCHUNK*12  per-chunk summaries
//  pref:   NCHUNK*12  in-block inclusive prefix summaries
//  wp:     NH*16      packed weights: w0..w5, benc, d0..d5, pad3
//  bsum:   SBLK*12    per-scan-block total summaries
#define REC_OFF    0
#define SUMM_OFF   ((size_t)NROW * 8)
#define PREF_OFF   (SUMM_OFF + (size_t)NCHUNK * 12)
#define WPACK_OFF  (PREF_OFF + (size_t)NCHUNK * 12)
#define BSUM_OFF   (WPACK_OFF + (size_t)NH * 16)

typedef __attribute__((ext_vector_type(16))) float f32x16;

__device__ __forceinline__ void qrotate(float qw, float qx, float qy, float qz,
                                        float vx, float vy, float vz,
                                        float& ox, float& oy, float& oz) {
    float tx = qy*vz - qz*vy + qw*vx;
    float ty = qz*vx - qx*vz + qw*vy;
    float tz = qx*vy - qy*vx + qw*vz;
    ox = vx + 2.0f*(qy*tz - qz*ty);
    oy = vy + 2.0f*(qz*tx - qx*tz);
    oz = vz + 2.0f*(qx*ty - qy*tx);
}

__device__ __forceinline__ void qmulf(float aw, float ax, float ay, float az,
                                      float bw, float bx, float by, float bz,
                                      float& ow, float& ox, float& oy, float& oz) {
    ow = aw*bw - ax*bx - ay*by - az*bz;
    ox = aw*bx + bw*ax + (ay*bz - az*by);
    oy = aw*by + bw*ay + (az*bx - ax*bz);
    oz = aw*bz + bw*az + (ax*by - ay*bx);
}

// quat_exp(w), |w| <= ~0.03: fp32-exact Taylor of cos(|w|/2), sin(|w|/2)/|w|.
__device__ __forceinline__ void qexpw(float wx, float wy, float wz,
                                      float& ew, float& ex, float& ey, float& ez) {
    float th2 = wx*wx + wy*wy + wz*wz + 1e-16f;
    float h2  = 0.25f * th2;
    ew = 1.0f + h2*(-0.5f + h2*((1.0f/24.0f) - h2*(1.0f/720.0f)));
    float sh = 0.5f + h2*(-(1.0f/12.0f) + h2*(1.0f/240.0f));
    ex = wx*sh; ey = wy*sh; ez = wz*sh;
}

// gelu tanh-approx via sigmoid: 0.5h(1+tanh(u)) = h / (1 + exp(-2u)).
// Constants pre-negated so no explicit negate. Saturates correctly at +-inf.
__device__ __forceinline__ float gelu_tanh(float h) {
    float h2 = h*h;
    float u2n = h*(-1.5957691216057308f - 0.0713548162726009f*h2);
    return __fdividef(h, 1.0f + __expf(u2n));
}

struct Sum { float Pw, Px, Py, Pz, T, S, Ux, Uy, Uz, Wx, Wy, Wz; };

__device__ __forceinline__ Sum compose(const Sum& a, const Sum& b) {
    Sum r;
    float RUx, RUy, RUz, RWx, RWy, RWz;
    qrotate(a.Pw, a.Px, a.Py, a.Pz, b.Ux, b.Uy, b.Uz, RUx, RUy, RUz);
    qrotate(a.Pw, a.Px, a.Py, a.Pz, b.Wx, b.Wy, b.Wz, RWx, RWy, RWz);
    r.Ux = a.Ux + RUx;  r.Uy = a.Uy + RUy;  r.Uz = a.Uz + RUz;
    r.Wx = a.Wx + a.Ux*b.T + RWx;
    r.Wy = a.Wy + a.Uy*b.T + RWy;
    r.Wz = a.Wz + a.Uz*b.T + RWz;
    r.S  = a.S + a.T*b.T + b.S;
    r.T  = a.T + b.T;
    float nw, nx, ny, nz;
    qmulf(a.Pw, a.Px, a.Py, a.Pz, b.Pw, b.Px, b.Py, b.Pz, nw, nx, ny, nz);
    float inv = 1.0f / sqrtf(nw*nw + nx*nx + ny*ny + nz*nz);
    r.Pw = nw*inv; r.Px = nx*inv; r.Py = ny*inv; r.Pz = nz*inv;
    return r;
}

__device__ __forceinline__ Sum shflDownSum(const Sum& s, int d) {
    Sum r;
    r.Pw = __shfl_down(s.Pw, d, 64); r.Px = __shfl_down(s.Px, d, 64);
    r.Py = __shfl_down(s.Py, d, 64); r.Pz = __shfl_down(s.Pz, d, 64);
    r.T  = __shfl_down(s.T,  d, 64); r.S  = __shfl_down(s.S,  d, 64);
    r.Ux = __shfl_down(s.Ux, d, 64); r.Uy = __shfl_down(s.Uy, d, 64);
    r.Uz = __shfl_down(s.Uz, d, 64); r.Wx = __shfl_down(s.Wx, d, 64);
    r.Wy = __shfl_down(s.Wy, d, 64); r.Wz = __shfl_down(s.Wz, d, 64);
    return r;
}

struct State { float px, py, pz, vx, vy, vz, qw, qx, qy, qz; };

__device__ __forceinline__ State applySum(const State& st, const Sum& s) {
    State r;
    float RUx, RUy, RUz, RWx, RWy, RWz;
    qrotate(st.qw, st.qx, st.qy, st.qz, s.Ux, s.Uy, s.Uz, RUx, RUy, RUz);
    qrotate(st.qw, st.qx, st.qy, st.qz, s.Wx, s.Wy, s.Wz, RWx, RWy, RWz);
    r.px = st.px + st.vx*s.T + RWx;
    r.py = st.py + st.vy*s.T + RWy;
    r.pz = st.pz + st.vz*s.T + RWz + GZ*s.S;
    r.vx = st.vx + RUx;
    r.vy = st.vy + RUy;
    r.vz = st.vz + RUz + GZ*s.T;
    float nw, nx, ny, nz;
    qmulf(st.qw, st.qx, st.qy, st.qz, s.Pw, s.Px, s.Py, s.Pz, nw, nx, ny, nz);
    float inv = 1.0f / sqrtf(nw*nw + nx*nx + ny*ny + nz*nz);
    r.qw = nw*inv; r.qx = nx*inv; r.qy = ny*inv; r.qz = nz*inv;
    return r;
}

__device__ __forceinline__ Sum loadSum(const float* __restrict__ p, int c) {
    const float* sp = p + (size_t)c*12;
    float4 a0 = ((const float4*)sp)[0];
    float4 a1 = ((const float4*)sp)[1];
    float4 a2 = ((const float4*)sp)[2];
    Sum s;
    s.Pw = a0.x; s.Px = a0.y; s.Py = a0.z; s.Pz = a0.w;
    s.T = a1.x; s.S = a1.y; s.Ux = a1.z; s.Uy = a1.w;
    s.Uz = a2.x; s.Wx = a2.y; s.Wy = a2.z; s.Wz = a2.w;
    return s;
}

__device__ __forceinline__ void storeSum(float* __restrict__ sp, const Sum& s) {
    ((float4*)sp)[0] = make_float4(s.Pw, s.Px, s.Py, s.Pz);
    ((float4*)sp)[1] = make_float4(s.T, s.S, s.Ux, s.Uy);
    ((float4*)sp)[2] = make_float4(s.Uz, s.Wx, s.Wy, s.Wz);
}

// ---- Kernel 0: pack weights into contiguous 64B/hidden-unit records ----
__global__ void repack_kernel(const float* __restrict__ Wenc, const float* __restrict__ benc,
                              const float* __restrict__ Wdec, float* __restrict__ wp) {
    int j = threadIdx.x;
    float* p = wp + j*16;
    p[0] = Wenc[0*NH+j]; p[1] = Wenc[1*NH+j]; p[2] = Wenc[2*NH+j];
    p[3] = Wenc[3*NH+j]; p[4] = Wenc[4*NH+j]; p[5] = Wenc[5*NH+j];
    p[6] = benc[j];
    p[7]  = Wdec[j*6+0]; p[8]  = Wdec[j*6+1]; p[9]  = Wdec[j*6+2];
    p[10] = Wdec[j*6+3]; p[11] = Wdec[j*6+4]; p[12] = Wdec[j*6+5];
    p[13] = 0.0f; p[14] = 0.0f; p[15] = 0.0f;
}

// ---- Kernel 1: MLP + record pack + per-chunk summaries.
// 64 rows/block (lane -> row), 4 waves split the 256 hidden units; one
// s_load_dwordx16 per j (ext_vector_type(16)). Epilogue spread over 3 waves.
__global__ __launch_bounds__(256)
void mlp_summ_kernel(const float* __restrict__ acc, const float* __restrict__ gyro,
                     const float* __restrict__ dtp, const float* __restrict__ wp,
                     const float* __restrict__ bdec,
                     float* __restrict__ out, float* __restrict__ rec,
                     float* __restrict__ summ) {
    __shared__ float part[4][64][8];
    int t = threadIdx.x;
    int lane = t & 63;
    int wv = __builtin_amdgcn_readfirstlane(t >> 6);
    int n = blockIdx.x * 64 + lane;
    float ax = acc[n*3+0], ay = acc[n*3+1], az = acc[n*3+2];
    float gx = gyro[n*3+0], gy = gyro[n*3+1], gz = gyro[n*3+2];
    float c0=0, c1=0, c2=0, c3=0, c4=0, c5=0;
    const f32x16* wbase = (const f32x16*)(wp) + wv*64;
    #pragma unroll 8
    for (int jj = 0; jj < 64; jj++) {
        f32x16 w = wbase[jj];                        // one s_load_dwordx16
        float h = w[6] + w[0]*ax + w[1]*ay + w[2]*az + w[3]*gx + w[4]*gy + w[5]*gz;
        float g = gelu_tanh(h);
        c0 += g*w[7];  c1 += g*w[8];  c2 += g*w[9];
        c3 += g*w[10]; c4 += g*w[11]; c5 += g*w[12];
    }
    float* pp = part[wv][lane];
    *(float4*)pp     = make_float4(c0, c1, c2, c3);
    *(float2*)(pp+4) = make_float2(c4, c5);
    __syncthreads();

    if (wv < 3) {
        int rl = lane;
        int rn = blockIdx.x * 64 + rl;
        float4 A = *(const float4*)part[0][rl];
        float2 B = *(const float2*)(part[0][rl]+4);
        #pragma unroll
        for (int w = 1; w < 4; w++) {
            float4 A2 = *(const float4*)part[w][rl];
            float2 B2 = *(const float2*)(part[w][rl]+4);
            A.x += A2.x; A.y += A2.y; A.z += A2.z; A.w += A2.w;
            B.x += B2.x; B.y += B2.y;
        }
        float e0 = A.x + bdec[0], e1 = A.y + bdec[1], e2 = A.z + bdec[2];
        float e3 = A.w + bdec[3], e4 = B.x + bdec[4], e5 = B.y + bdec[5];

        if (wv == 2) {
            float* ob = out + (size_t)rn*16;
            *(float2*)(ob+10) = make_float2(e0, e1);
            *(float4*)(ob+12) = make_float4(e2, e3, e4, e5);
        } else {
            float dtv = dtp[rn];
            float cax = e0 + acc[rn*3+0], cay = e1 + acc[rn*3+1], caz = e2 + acc[rn*3+2];
            float cgx = e3 + gyro[rn*3+0], cgy = e4 + gyro[rn*3+1], cgz = e5 + gyro[rn*3+2];
            if (wv == 1) {
                int ci = rn >> 2, ii = rn & 3;       // CL = 4
                float* rp = rec + (size_t)(ii*NCHUNK + ci)*8;
                *(float4*)rp     = make_float4(cax, cay, caz, cgx);
                *(float4*)(rp+4) = make_float4(cgy, cgz, dtv, 0.0f);
            } else {
                Sum s;
                float hdt2 = 0.5f*dtv*dtv;
                qexpw(cgx*dtv, cgy*dtv, cgz*dtv, s.Pw, s.Px, s.Py, s.Pz);
                s.T = dtv; s.S = hdt2;
                s.Ux = cax*dtv;  s.Uy = cay*dtv;  s.Uz = caz*dtv;
                s.Wx = cax*hdt2; s.Wy = cay*hdt2; s.Wz = caz*hdt2;
                Sum nb = shflDownSum(s, 1);
                s = compose(s, nb);                  // valid at even lanes
                nb = shflDownSum(s, 2);
                s = compose(s, nb);                  // valid at lane%4==0
                if ((rl & 3) == 0) storeSum(summ + (size_t)(rn >> 2)*12, s);
            }
        }
    }
}

// ---- Kernel 2: in-block inclusive scan (one thread per chunk, 8 LDS rounds) ----
__global__ __launch_bounds__(256)
void scan1(const float* __restrict__ summ, float* __restrict__ pref,
           float* __restrict__ bsum) {
    __shared__ float lds[256*13];                   // stride 13: conflict-free
    int t = threadIdx.x;
    int c = blockIdx.x * 256 + t;
    Sum agg = loadSum(summ, c);
    float* mine = lds + t*13;
    mine[0]=agg.Pw; mine[1]=agg.Px; mine[2]=agg.Py; mine[3]=agg.Pz;
    mine[4]=agg.T;  mine[5]=agg.S;  mine[6]=agg.Ux; mine[7]=agg.Uy;
    mine[8]=agg.Uz; mine[9]=agg.Wx; mine[10]=agg.Wy; mine[11]=agg.Wz;
    __syncthreads();
    for (int d = 1; d < 256; d <<= 1) {
        Sum left;
        bool have = (t >= d);
        if (have) {
            const float* lp = lds + (t-d)*13;
            left.Pw=lp[0]; left.Px=lp[1]; left.Py=lp[2]; left.Pz=lp[3];
            left.T=lp[4];  left.S=lp[5];  left.Ux=lp[6]; left.Uy=lp[7];
            left.Uz=lp[8]; left.Wx=lp[9]; left.Wy=lp[10]; left.Wz=lp[11];
        }
        __syncthreads();
        if (have) {
            agg = compose(left, agg);
            mine[0]=agg.Pw; mine[1]=agg.Px; mine[2]=agg.Py; mine[3]=agg.Pz;
            mine[4]=agg.T;  mine[5]=agg.S;  mine[6]=agg.Ux; mine[7]=agg.Uy;
            mine[8]=agg.Uz; mine[9]=agg.Wx; mine[10]=agg.Wy; mine[11]=agg.Wz;
        }
        __syncthreads();
    }
    storeSum(pref + (size_t)c*12, agg);
    if (t == 255) storeSum(bsum + (size_t)blockIdx.x*12, agg);
}

// ---- Kernel 3: phaseC with inlined block-state combine (was scan2).
// Thread 0 composes init state with the <=15 preceding block totals; broadcast
// via LDS; each thread then offsets by pref[c-1] and replays its 4 steps.
__global__ __launch_bounds__(256)
void phaseC(const float* __restrict__ rec, const float* __restrict__ pref,
            const float* __restrict__ bsum,
            const float* __restrict__ init_pos, const float* __restrict__ init_vel,
            const float* __restrict__ init_rot, float* __restrict__ out) {
    __shared__ float bst[12];
    int t = threadIdx.x;
    int c = blockIdx.x * 256 + t;
    if (t == 0) {
        int b = blockIdx.x / BPB;
        int k0 = blockIdx.x % BPB;
        State st;
        st.px = init_pos[b*3+0]; st.py = init_pos[b*3+1]; st.pz = init_pos[b*3+2];
        st.vx = init_vel[b*3+0]; st.vy = init_vel[b*3+1]; st.vz = init_vel[b*3+2];
        st.qw = init_rot[b*4+0]; st.qx = init_rot[b*4+1]; st.qy = init_rot[b*4+2]; st.qz = init_rot[b*4+3];
        for (int k = 0; k < k0; k++)
            st = applySum(st, loadSum(bsum, b*BPB + k));
        bst[0]=st.px; bst[1]=st.py; bst[2]=st.pz; bst[3]=st.vx; bst[4]=st.vy;
        bst[5]=st.vz; bst[6]=st.qw; bst[7]=st.qx; bst[8]=st.qy; bst[9]=st.qz;
    }
    __syncthreads();
    State st;
    st.px = bst[0]; st.py = bst[1]; st.pz = bst[2];
    st.vx = bst[3]; st.vy = bst[4]; st.vz = bst[5];
    st.qw = bst[6]; st.qx = bst[7]; st.qy = bst[8]; st.qz = bst[9];
    if (t > 0) st = applySum(st, loadSum(pref, c-1));
    float px = st.px, py = st.py, pz = st.pz;
    float vx = st.vx, vy = st.vy, vz = st.vz;
    float qw = st.qw, qx = st.qx, qy = st.qy, qz = st.qz;
    const float4* r = (const float4*)rec;
    float* obase = out + (size_t)c*CL*16;
    #pragma unroll
    for (int i = 0; i < CL; i++) {
        float4 r0 = r[(size_t)(i*NCHUNK + c)*2];
        float4 r1 = r[(size_t)(i*NCHUNK + c)*2 + 1];
        float dtv = r1.z;
        float awx, awy, awz;
        qrotate(qw, qx, qy, qz, r0.x, r0.y, r0.z, awx, awy, awz);
        awz += GZ;
        float hdt2 = 0.5f*dtv*dtv;
        px += vx*dtv + awx*hdt2;
        py += vy*dtv + awy*hdt2;
        pz += vz*dtv + awz*hdt2;
        vx += awx*dtv; vy += awy*dtv; vz += awz*dtv;
        float ew, ex, ey, ez, nw, nx, ny, nz;
        qexpw(r0.w*dtv, r1.x*dtv, r1.y*dtv, ew, ex, ey, ez);
        qmulf(qw, qx, qy, qz, ew, ex, ey, ez, nw, nx, ny, nz);
        float inv = 1.0f / sqrtf(nw*nw + nx*nx + ny*ny + nz*nz);
        qw = nw*inv; qx = nx*inv; qy = ny*inv; qz = nz*inv;
        float* ob = obase + (size_t)i*16;
        *(float4*)(ob+0) = make_float4(px, py, pz, vx);
        *(float4*)(ob+4) = make_float4(vy, vz, qw, qx);
        *(float2*)(ob+8) = make_float2(qy, qz);
    }
}

extern "C" void kernel_launch(void* const* d_in, const int* in_sizes, int n_in,
                              void* d_out, int out_size, void* d_ws, size_t ws_size,
                              hipStream_t stream) {
    const float* acc      = (const float*)d_in[0];
    const float* gyro     = (const float*)d_in[1];
    const float* dt       = (const float*)d_in[2];
    const float* init_pos = (const float*)d_in[3];
    const float* init_vel = (const float*)d_in[4];
    const float* init_rot = (const float*)d_in[5];
    const float* Wenc     = (const float*)d_in[6];
    const float* benc     = (const float*)d_in[7];
    const float* Wdec     = (const float*)d_in[8];
    const float* bdec     = (const float*)d_in[9];
    float* out = (float*)d_out;
    float* ws  = (float*)d_ws;
    float* rec    = ws + REC_OFF;
    float* summ   = ws + SUMM_OFF;
    float* pref   = ws + PREF_OFF;
    float* wp     = ws + WPACK_OFF;
    float* bsum   = ws + BSUM_OFF;

    repack_kernel<<<1, NH, 0, stream>>>(Wenc, benc, Wdec, wp);
    mlp_summ_kernel<<<NROW/64, 256, 0, stream>>>(acc, gyro, dt, wp, bdec, out, rec, summ);
    scan1<<<SBLK, 256, 0, stream>>>(summ, pref, bsum);
    phaseC<<<SBLK, 256, 0, stream>>>(rec, pref, bsum, init_pos, init_vel, init_rot, out);
}

// Round 11
// 127.021 us; speedup vs baseline: 1.4178x; 1.0051x over previous
//
#include <hip/hip_runtime.h>
#include <math.h>

#define NB 8
#define NF 16384
#define NH 256
#define CL 4                   // steps per chunk
#define CPB (NF / CL)          // 4096 chunks per batch
#define NCHUNK (NB * CPB)      // 32768 chunks
#define NROW (NB * NF)         // 131072 rows
#define SBLK (NCHUNK / 256)    // 128 scan blocks (16 per batch)
#define BPB (CPB / 256)        // 16 scan blocks per batch

#define GZ -9.81007f

// ws layout (floats):
//  rec:    NROW*8     transposed records [i*NCHUNK+c]*8 = ca3, cg3, dt, pad
//  summ:   NCHUNK*12  per-chunk summaries
//  pref:   NCHUNK*12  in-block inclusive prefix summaries
//  wp:     NH*16      packed weights: w0..w5, benc, d0..d5, pad3
//  bsum:   SBLK*12    per-scan-block total summaries
#define REC_OFF    0
#define SUMM_OFF   ((size_t)NROW * 8)
#define PREF_OFF   (SUMM_OFF + (size_t)NCHUNK * 12)
#define WPACK_OFF  (PREF_OFF + (size_t)NCHUNK * 12)
#define BSUM_OFF   (WPACK_OFF + (size_t)NH * 16)

typedef __attribute__((ext_vector_type(16))) float f32x16;

__device__ __forceinline__ void qrotate(float qw, float qx, float qy, float qz,
                                        float vx, float vy, float vz,
                                        float& ox, float& oy, float& oz) {
    float tx = qy*vz - qz*vy + qw*vx;
    float ty = qz*vx - qx*vz + qw*vy;
    float tz = qx*vy - qy*vx + qw*vz;
    ox = vx + 2.0f*(qy*tz - qz*ty);
    oy = vy + 2.0f*(qz*tx - qx*tz);
    oz = vz + 2.0f*(qx*ty - qy*tx);
}

__device__ __forceinline__ void qmulf(float aw, float ax, float ay, float az,
                                      float bw, float bx, float by, float bz,
                                      float& ow, float& ox, float& oy, float& oz) {
    ow = aw*bw - ax*bx - ay*by - az*bz;
    ox = aw*bx + bw*ax + (ay*bz - az*by);
    oy = aw*by + bw*ay + (az*bx - ax*bz);
    oz = aw*bz + bw*az + (ax*by - ay*bx);
}

// quat_exp(w), |w| <= ~0.03: fp32-exact Taylor of cos(|w|/2), sin(|w|/2)/|w|.
__device__ __forceinline__ void qexpw(float wx, float wy, float wz,
                                      float& ew, float& ex, float& ey, float& ez) {
    float th2 = wx*wx + wy*wy + wz*wz + 1e-16f;
    float h2  = 0.25f * th2;
    ew = 1.0f + h2*(-0.5f + h2*((1.0f/24.0f) - h2*(1.0f/720.0f)));
    float sh = 0.5f + h2*(-(1.0f/12.0f) + h2*(1.0f/240.0f));
    ex = wx*sh; ey = wy*sh; ez = wz*sh;
}

// gelu tanh-approx via sigmoid: 0.5h(1+tanh(u)) = h / (1 + exp(-2u)).
__device__ __forceinline__ float gelu_tanh(float h) {
    float h2 = h*h;
    float u2n = h*(-1.5957691216057308f - 0.0713548162726009f*h2);
    return __fdividef(h, 1.0f + __expf(u2n));
}

struct Sum { float Pw, Px, Py, Pz, T, S, Ux, Uy, Uz, Wx, Wy, Wz; };

__device__ __forceinline__ Sum compose(const Sum& a, const Sum& b) {
    Sum r;
    float RUx, RUy, RUz, RWx, RWy, RWz;
    qrotate(a.Pw, a.Px, a.Py, a.Pz, b.Ux, b.Uy, b.Uz, RUx, RUy, RUz);
    qrotate(a.Pw, a.Px, a.Py, a.Pz, b.Wx, b.Wy, b.Wz, RWx, RWy, RWz);
    r.Ux = a.Ux + RUx;  r.Uy = a.Uy + RUy;  r.Uz = a.Uz + RUz;
    r.Wx = a.Wx + a.Ux*b.T + RWx;
    r.Wy = a.Wy + a.Uy*b.T + RWy;
    r.Wz = a.Wz + a.Uz*b.T + RWz;
    r.S  = a.S + a.T*b.T + b.S;
    r.T  = a.T + b.T;
    float nw, nx, ny, nz;
    qmulf(a.Pw, a.Px, a.Py, a.Pz, b.Pw, b.Px, b.Py, b.Pz, nw, nx, ny, nz);
    float inv = 1.0f / sqrtf(nw*nw + nx*nx + ny*ny + nz*nz);
    r.Pw = nw*inv; r.Px = nx*inv; r.Py = ny*inv; r.Pz = nz*inv;
    return r;
}

__device__ __forceinline__ Sum shflDownSum(const Sum& s, int d) {
    Sum r;
    r.Pw = __shfl_down(s.Pw, d, 64); r.Px = __shfl_down(s.Px, d, 64);
    r.Py = __shfl_down(s.Py, d, 64); r.Pz = __shfl_down(s.Pz, d, 64);
    r.T  = __shfl_down(s.T,  d, 64); r.S  = __shfl_down(s.S,  d, 64);
    r.Ux = __shfl_down(s.Ux, d, 64); r.Uy = __shfl_down(s.Uy, d, 64);
    r.Uz = __shfl_down(s.Uz, d, 64); r.Wx = __shfl_down(s.Wx, d, 64);
    r.Wy = __shfl_down(s.Wy, d, 64); r.Wz = __shfl_down(s.Wz, d, 64);
    return r;
}

struct State { float px, py, pz, vx, vy, vz, qw, qx, qy, qz; };

__device__ __forceinline__ State applySum(const State& st, const Sum& s) {
    State r;
    float RUx, RUy, RUz, RWx, RWy, RWz;
    qrotate(st.qw, st.qx, st.qy, st.qz, s.Ux, s.Uy, s.Uz, RUx, RUy, RUz);
    qrotate(st.qw, st.qx, st.qy, st.qz, s.Wx, s.Wy, s.Wz, RWx, RWy, RWz);
    r.px = st.px + st.vx*s.T + RWx;
    r.py = st.py + st.vy*s.T + RWy;
    r.pz = st.pz + st.vz*s.T + RWz + GZ*s.S;
    r.vx = st.vx + RUx;
    r.vy = st.vy + RUy;
    r.vz = st.vz + RUz + GZ*s.T;
    float nw, nx, ny, nz;
    qmulf(st.qw, st.qx, st.qy, st.qz, s.Pw, s.Px, s.Py, s.Pz, nw, nx, ny, nz);
    float inv = 1.0f / sqrtf(nw*nw + nx*nx + ny*ny + nz*nz);
    r.qw = nw*inv; r.qx = nx*inv; r.qy = ny*inv; r.qz = nz*inv;
    return r;
}

__device__ __forceinline__ Sum loadSum(const float* __restrict__ p, int c) {
    const float* sp = p + (size_t)c*12;
    float4 a0 = ((const float4*)sp)[0];
    float4 a1 = ((const float4*)sp)[1];
    float4 a2 = ((const float4*)sp)[2];
    Sum s;
    s.Pw = a0.x; s.Px = a0.y; s.Py = a0.z; s.Pz = a0.w;
    s.T = a1.x; s.S = a1.y; s.Ux = a1.z; s.Uy = a1.w;
    s.Uz = a2.x; s.Wx = a2.y; s.Wy = a2.z; s.Wz = a2.w;
    return s;
}

__device__ __forceinline__ void storeSum(float* __restrict__ sp, const Sum& s) {
    ((float4*)sp)[0] = make_float4(s.Pw, s.Px, s.Py, s.Pz);
    ((float4*)sp)[1] = make_float4(s.T, s.S, s.Ux, s.Uy);
    ((float4*)sp)[2] = make_float4(s.Uz, s.Wx, s.Wy, s.Wz);
}

// ---- Kernel 0: pack weights into contiguous 64B/hidden-unit records ----
__global__ void repack_kernel(const float* __restrict__ Wenc, const float* __restrict__ benc,
                              const float* __restrict__ Wdec, float* __restrict__ wp) {
    int j = threadIdx.x;
    float* p = wp + j*16;
    p[0] = Wenc[0*NH+j]; p[1] = Wenc[1*NH+j]; p[2] = Wenc[2*NH+j];
    p[3] = Wenc[3*NH+j]; p[4] = Wenc[4*NH+j]; p[5] = Wenc[5*NH+j];
    p[6] = benc[j];
    p[7]  = Wdec[j*6+0]; p[8]  = Wdec[j*6+1]; p[9]  = Wdec[j*6+2];
    p[10] = Wdec[j*6+3]; p[11] = Wdec[j*6+4]; p[12] = Wdec[j*6+5];
    p[13] = 0.0f; p[14] = 0.0f; p[15] = 0.0f;
}

// ---- Kernel 1: MLP + record pack + per-chunk summaries.
// 128 rows/block, 2 rows per lane (doubles VALU work per s_load_dwordx16 and
// gives the SLP vectorizer two identical independent chains -> v_pk_fma_f32);
// 4 waves split the 256 hidden units. Epilogue: waves0/1 -> rec+summ for rows
// 0..127, waves2/3 -> out correction for rows 0..127.
__global__ __launch_bounds__(256)
void mlp_summ_kernel(const float* __restrict__ acc, const float* __restrict__ gyro,
                     const float* __restrict__ dtp, const float* __restrict__ wp,
                     const float* __restrict__ bdec,
                     float* __restrict__ out, float* __restrict__ rec,
                     float* __restrict__ summ) {
    __shared__ float part[4][128][8];               // 16 KB
    int t = threadIdx.x;
    int lane = t & 63;
    int wv = __builtin_amdgcn_readfirstlane(t >> 6);
    int base = blockIdx.x * 128;
    int n0 = base + lane;
    int n1 = base + 64 + lane;
    float ax0 = acc[n0*3+0], ay0 = acc[n0*3+1], az0 = acc[n0*3+2];
    float gx0 = gyro[n0*3+0], gy0 = gyro[n0*3+1], gz0 = gyro[n0*3+2];
    float ax1 = acc[n1*3+0], ay1 = acc[n1*3+1], az1 = acc[n1*3+2];
    float gx1 = gyro[n1*3+0], gy1 = gyro[n1*3+1], gz1 = gyro[n1*3+2];
    float c0a=0, c1a=0, c2a=0, c3a=0, c4a=0, c5a=0;
    float c0b=0, c1b=0, c2b=0, c3b=0, c4b=0, c5b=0;
    const f32x16* wbase = (const f32x16*)(wp) + wv*64;
    #pragma unroll 8
    for (int jj = 0; jj < 64; jj++) {
        f32x16 w = wbase[jj];                       // one s_load_dwordx16
        float ha = w[6] + w[0]*ax0 + w[1]*ay0 + w[2]*az0 + w[3]*gx0 + w[4]*gy0 + w[5]*gz0;
        float hb = w[6] + w[0]*ax1 + w[1]*ay1 + w[2]*az1 + w[3]*gx1 + w[4]*gy1 + w[5]*gz1;
        float ga = gelu_tanh(ha);
        float gb = gelu_tanh(hb);
        c0a += ga*w[7];  c0b += gb*w[7];
        c1a += ga*w[8];  c1b += gb*w[8];
        c2a += ga*w[9];  c2b += gb*w[9];
        c3a += ga*w[10]; c3b += gb*w[10];
        c4a += ga*w[11]; c4b += gb*w[11];
        c5a += ga*w[12]; c5b += gb*w[12];
    }
    {
        float* pa = part[wv][lane];
        *(float4*)pa     = make_float4(c0a, c1a, c2a, c3a);
        *(float2*)(pa+4) = make_float2(c4a, c5a);
        float* pb = part[wv][64 + lane];
        *(float4*)pb     = make_float4(c0b, c1b, c2b, c3b);
        *(float2*)(pb+4) = make_float2(c4b, c5b);
    }
    __syncthreads();

    int rl = t & 127;                               // row-local 0..127
    int task = t >> 7;                              // 0: rec+summ, 1: out
    int rn = base + rl;
    float4 A = *(const float4*)part[0][rl];
    float2 B = *(const float2*)(part[0][rl]+4);
    #pragma unroll
    for (int w = 1; w < 4; w++) {
        float4 A2 = *(const float4*)part[w][rl];
        float2 B2 = *(const float2*)(part[w][rl]+4);
        A.x += A2.x; A.y += A2.y; A.z += A2.z; A.w += A2.w;
        B.x += B2.x; B.y += B2.y;
    }
    float e0 = A.x + bdec[0], e1 = A.y + bdec[1], e2 = A.z + bdec[2];
    float e3 = A.w + bdec[3], e4 = B.x + bdec[4], e5 = B.y + bdec[5];

    if (task == 1) {
        float* ob = out + (size_t)rn*16;
        *(float2*)(ob+10) = make_float2(e0, e1);
        *(float4*)(ob+12) = make_float4(e2, e3, e4, e5);
    } else {
        float dtv = dtp[rn];
        float cax = e0 + acc[rn*3+0], cay = e1 + acc[rn*3+1], caz = e2 + acc[rn*3+2];
        float cgx = e3 + gyro[rn*3+0], cgy = e4 + gyro[rn*3+1], cgz = e5 + gyro[rn*3+2];
        int ci = rn >> 2, ii = rn & 3;              // CL = 4
        float* rp = rec + (size_t)(ii*NCHUNK + ci)*8;
        *(float4*)rp     = make_float4(cax, cay, caz, cgx);
        *(float4*)(rp+4) = make_float4(cgy, cgz, dtv, 0.0f);

        // per-chunk summary: rows are lane-consecutive within waves 0 and 1
        Sum s;
        float hdt2 = 0.5f*dtv*dtv;
        qexpw(cgx*dtv, cgy*dtv, cgz*dtv, s.Pw, s.Px, s.Py, s.Pz);
        s.T = dtv; s.S = hdt2;
        s.Ux = cax*dtv;  s.Uy = cay*dtv;  s.Uz = caz*dtv;
        s.Wx = cax*hdt2; s.Wy = cay*hdt2; s.Wz = caz*hdt2;
        Sum nb = shflDownSum(s, 1);
        s = compose(s, nb);                         // valid at even lanes
        nb = shflDownSum(s, 2);
        s = compose(s, nb);                         // valid at lane%4==0
        if ((rl & 3) == 0) storeSum(summ + (size_t)(rn >> 2)*12, s);
    }
}

// ---- Kernel 2: in-block inclusive scan (one thread per chunk, 8 LDS rounds) ----
__global__ __launch_bounds__(256)
void scan1(const float* __restrict__ summ, float* __restrict__ pref,
           float* __restrict__ bsum) {
    __shared__ float lds[256*13];                   // stride 13: conflict-free
    int t = threadIdx.x;
    int c = blockIdx.x * 256 + t;
    Sum agg = loadSum(summ, c);
    float* mine = lds + t*13;
    mine[0]=agg.Pw; mine[1]=agg.Px; mine[2]=agg.Py; mine[3]=agg.Pz;
    mine[4]=agg.T;  mine[5]=agg.S;  mine[6]=agg.Ux; mine[7]=agg.Uy;
    mine[8]=agg.Uz; mine[9]=agg.Wx; mine[10]=agg.Wy; mine[11]=agg.Wz;
    __syncthreads();
    for (int d = 1; d < 256; d <<= 1) {
        Sum left;
        bool have = (t >= d);
        if (have) {
            const float* lp = lds + (t-d)*13;
            left.Pw=lp[0]; left.Px=lp[1]; left.Py=lp[2]; left.Pz=lp[3];
            left.T=lp[4];  left.S=lp[5];  left.Ux=lp[6]; left.Uy=lp[7];
            left.Uz=lp[8]; left.Wx=lp[9]; left.Wy=lp[10]; left.Wz=lp[11];
        }
        __syncthreads();
        if (have) {
            agg = compose(left, agg);
            mine[0]=agg.Pw; mine[1]=agg.Px; mine[2]=agg.Py; mine[3]=agg.Pz;
            mine[4]=agg.T;  mine[5]=agg.S;  mine[6]=agg.Ux; mine[7]=agg.Uy;
            mine[8]=agg.Uz; mine[9]=agg.Wx; mine[10]=agg.Wy; mine[11]=agg.Wz;
        }
        __syncthreads();
    }
    storeSum(pref + (size_t)c*12, agg);
    if (t == 255) storeSum(bsum + (size_t)blockIdx.x*12, agg);
}

// ---- Kernel 3: phaseC with inlined block-state combine.
__global__ __launch_bounds__(256)
void phaseC(const float* __restrict__ rec, const float* __restrict__ pref,
            const float* __restrict__ bsum,
            const float* __restrict__ init_pos, const float* __restrict__ init_vel,
            const float* __restrict__ init_rot, float* __restrict__ out) {
    __shared__ float bst[12];
    int t = threadIdx.x;
    int c = blockIdx.x * 256 + t;
    if (t == 0) {
        int b = blockIdx.x / BPB;
        int k0 = blockIdx.x % BPB;
        State st;
        st.px = init_pos[b*3+0]; st.py = init_pos[b*3+1]; st.pz = init_pos[b*3+2];
        st.vx = init_vel[b*3+0]; st.vy = init_vel[b*3+1]; st.vz = init_vel[b*3+2];
        st.qw = init_rot[b*4+0]; st.qx = init_rot[b*4+1]; st.qy = init_rot[b*4+2]; st.qz = init_rot[b*4+3];
        for (int k = 0; k < k0; k++)
            st = applySum(st, loadSum(bsum, b*BPB + k));
        bst[0]=st.px; bst[1]=st.py; bst[2]=st.pz; bst[3]=st.vx; bst[4]=st.vy;
        bst[5]=st.vz; bst[6]=st.qw; bst[7]=st.qx; bst[8]=st.qy; bst[9]=st.qz;
    }
    __syncthreads();
    State st;
    st.px = bst[0]; st.py = bst[1]; st.pz = bst[2];
    st.vx = bst[3]; st.vy = bst[4]; st.vz = bst[5];
    st.qw = bst[6]; st.qx = bst[7]; st.qy = bst[8]; st.qz = bst[9];
    if (t > 0) st = applySum(st, loadSum(pref, c-1));
    float px = st.px, py = st.py, pz = st.pz;
    float vx = st.vx, vy = st.vy, vz = st.vz;
    float qw = st.qw, qx = st.qx, qy = st.qy, qz = st.qz;
    const float4* r = (const float4*)rec;
    float* obase = out + (size_t)c*CL*16;
    #pragma unroll
    for (int i = 0; i < CL; i++) {
        float4 r0 = r[(size_t)(i*NCHUNK + c)*2];
        float4 r1 = r[(size_t)(i*NCHUNK + c)*2 + 1];
        float dtv = r1.z;
        float awx, awy, awz;
        qrotate(qw, qx, qy, qz, r0.x, r0.y, r0.z, awx, awy, awz);
        awz += GZ;
        float hdt2 = 0.5f*dtv*dtv;
        px += vx*dtv + awx*hdt2;
        py += vy*dtv + awy*hdt2;
        pz += vz*dtv + awz*hdt2;
        vx += awx*dtv; vy += awy*dtv; vz += awz*dtv;
        float ew, ex, ey, ez, nw, nx, ny, nz;
        qexpw(r0.w*dtv, r1.x*dtv, r1.y*dtv, ew, ex, ey, ez);
        qmulf(qw, qx, qy, qz, ew, ex, ey, ez, nw, nx, ny, nz);
        float inv = 1.0f / sqrtf(nw*nw + nx*nx + ny*ny + nz*nz);
        qw = nw*inv; qx = nx*inv; qy = ny*inv; qz = nz*inv;
        float* ob = obase + (size_t)i*16;
        *(float4*)(ob+0) = make_float4(px, py, pz, vx);
        *(float4*)(ob+4) = make_float4(vy, vz, qw, qx);
        *(float2*)(ob+8) = make_float2(qy, qz);
    }
}

extern "C" void kernel_launch(void* const* d_in, const int* in_sizes, int n_in,
                              void* d_out, int out_size, void* d_ws, size_t ws_size,
                              hipStream_t stream) {
    const float* acc      = (const float*)d_in[0];
    const float* gyro     = (const float*)d_in[1];
    const float* dt       = (const float*)d_in[2];
    const float* init_pos = (const float*)d_in[3];
    const float* init_vel = (const float*)d_in[4];
    const float* init_rot = (const float*)d_in[5];
    const float* Wenc     = (const float*)d_in[6];
    const float* benc     = (const float*)d_in[7];
    const float* Wdec     = (const float*)d_in[8];
    const float* bdec     = (const float*)d_in[9];
    float* out = (float*)d_out;
    float* ws  = (float*)d_ws;
    float* rec    = ws + REC_OFF;
    float* summ   = ws + SUMM_OFF;
    float* pref   = ws + PREF_OFF;
    float* wp     = ws + WPACK_OFF;
    float* bsum   = ws + BSUM_OFF;

    repack_kernel<<<1, NH, 0, stream>>>(Wenc, benc, Wdec, wp);
    mlp_summ_kernel<<<NROW/128, 256, 0, stream>>>(acc, gyro, dt, wp, bdec, out, rec, summ);
    scan1<<<SBLK, 256, 0, stream>>>(summ, pref, bsum);
    phaseC<<<SBLK, 256, 0, stream>>>(rec, pref, bsum, init_pos, init_vel, init_rot, out);
}

// Round 12
// 119.457 us; speedup vs baseline: 1.5076x; 1.0633x over previous
//
#include <hip/hip_runtime.h>
#include <math.h>

#define NB 8
#define NF 16384
#define NH 256
#define CL 4                   // steps per chunk
#define CPB (NF / CL)          // 4096 chunks per batch
#define NCHUNK (NB * CPB)      // 32768 chunks
#define NROW (NB * NF)         // 131072 rows
#define SBLK (NCHUNK / 256)    // 128 scan blocks (16 per batch)
#define BPB (CPB / 256)        // 16 scan blocks per batch

#define GZ -9.81007f

// ws layout (floats):
//  rec:    NROW*8     transposed records [i*NCHUNK+c]*8 = ca3, cg3, dt, pad
//  summ:   NCHUNK*12  per-chunk summaries
//  pref:   NCHUNK*12  in-block inclusive prefix summaries
//  wp:     NH*16      packed weights: w0..w5, benc, d0..d5, pad3
//  bsum:   SBLK*12    per-scan-block total summaries
#define REC_OFF    0
#define SUMM_OFF   ((size_t)NROW * 8)
#define PREF_OFF   (SUMM_OFF + (size_t)NCHUNK * 12)
#define WPACK_OFF  (PREF_OFF + (size_t)NCHUNK * 12)
#define BSUM_OFF   (WPACK_OFF + (size_t)NH * 16)

typedef __attribute__((ext_vector_type(16))) float f32x16;
typedef __attribute__((ext_vector_type(2)))  float f32x2;

__device__ __forceinline__ void qrotate(float qw, float qx, float qy, float qz,
                                        float vx, float vy, float vz,
                                        float& ox, float& oy, float& oz) {
    float tx = qy*vz - qz*vy + qw*vx;
    float ty = qz*vx - qx*vz + qw*vy;
    float tz = qx*vy - qy*vx + qw*vz;
    ox = vx + 2.0f*(qy*tz - qz*ty);
    oy = vy + 2.0f*(qz*tx - qx*tz);
    oz = vz + 2.0f*(qx*ty - qy*tx);
}

__device__ __forceinline__ void qmulf(float aw, float ax, float ay, float az,
                                      float bw, float bx, float by, float bz,
                                      float& ow, float& ox, float& oy, float& oz) {
    ow = aw*bw - ax*bx - ay*by - az*bz;
    ox = aw*bx + bw*ax + (ay*bz - az*by);
    oy = aw*by + bw*ay + (az*bx - ax*bz);
    oz = aw*bz + bw*az + (ax*by - ay*bx);
}

// quat_exp(w), |w| <= ~0.03: fp32-exact Taylor of cos(|w|/2), sin(|w|/2)/|w|.
__device__ __forceinline__ void qexpw(float wx, float wy, float wz,
                                      float& ew, float& ex, float& ey, float& ez) {
    float th2 = wx*wx + wy*wy + wz*wz + 1e-16f;
    float h2  = 0.25f * th2;
    ew = 1.0f + h2*(-0.5f + h2*((1.0f/24.0f) - h2*(1.0f/720.0f)));
    float sh = 0.5f + h2*(-(1.0f/12.0f) + h2*(1.0f/240.0f));
    ex = wx*sh; ey = wy*sh; ez = wz*sh;
}

// gelu tanh-approx via sigmoid: 0.5h(1+tanh(u)) = h / (1 + exp(-2u)).
__device__ __forceinline__ float gelu_tanh(float h) {
    float h2 = h*h;
    float u2n = h*(-1.5957691216057308f - 0.0713548162726009f*h2);
    return __fdividef(h, 1.0f + __expf(u2n));
}

struct Sum { float Pw, Px, Py, Pz, T, S, Ux, Uy, Uz, Wx, Wy, Wz; };

__device__ __forceinline__ Sum compose(const Sum& a, const Sum& b) {
    Sum r;
    float RUx, RUy, RUz, RWx, RWy, RWz;
    qrotate(a.Pw, a.Px, a.Py, a.Pz, b.Ux, b.Uy, b.Uz, RUx, RUy, RUz);
    qrotate(a.Pw, a.Px, a.Py, a.Pz, b.Wx, b.Wy, b.Wz, RWx, RWy, RWz);
    r.Ux = a.Ux + RUx;  r.Uy = a.Uy + RUy;  r.Uz = a.Uz + RUz;
    r.Wx = a.Wx + a.Ux*b.T + RWx;
    r.Wy = a.Wy + a.Uy*b.T + RWy;
    r.Wz = a.Wz + a.Uz*b.T + RWz;
    r.S  = a.S + a.T*b.T + b.S;
    r.T  = a.T + b.T;
    float nw, nx, ny, nz;
    qmulf(a.Pw, a.Px, a.Py, a.Pz, b.Pw, b.Px, b.Py, b.Pz, nw, nx, ny, nz);
    float inv = 1.0f / sqrtf(nw*nw + nx*nx + ny*ny + nz*nz);
    r.Pw = nw*inv; r.Px = nx*inv; r.Py = ny*inv; r.Pz = nz*inv;
    return r;
}

__device__ __forceinline__ Sum shflDownSum(const Sum& s, int d) {
    Sum r;
    r.Pw = __shfl_down(s.Pw, d, 64); r.Px = __shfl_down(s.Px, d, 64);
    r.Py = __shfl_down(s.Py, d, 64); r.Pz = __shfl_down(s.Pz, d, 64);
    r.T  = __shfl_down(s.T,  d, 64); r.S  = __shfl_down(s.S,  d, 64);
    r.Ux = __shfl_down(s.Ux, d, 64); r.Uy = __shfl_down(s.Uy, d, 64);
    r.Uz = __shfl_down(s.Uz, d, 64); r.Wx = __shfl_down(s.Wx, d, 64);
    r.Wy = __shfl_down(s.Wy, d, 64); r.Wz = __shfl_down(s.Wz, d, 64);
    return r;
}

struct State { float px, py, pz, vx, vy, vz, qw, qx, qy, qz; };

__device__ __forceinline__ State applySum(const State& st, const Sum& s) {
    State r;
    float RUx, RUy, RUz, RWx, RWy, RWz;
    qrotate(st.qw, st.qx, st.qy, st.qz, s.Ux, s.Uy, s.Uz, RUx, RUy, RUz);
    qrotate(st.qw, st.qx, st.qy, st.qz, s.Wx, s.Wy, s.Wz, RWx, RWy, RWz);
    r.px = st.px + st.vx*s.T + RWx;
    r.py = st.py + st.vy*s.T + RWy;
    r.pz = st.pz + st.vz*s.T + RWz + GZ*s.S;
    r.vx = st.vx + RUx;
    r.vy = st.vy + RUy;
    r.vz = st.vz + RUz + GZ*s.T;
    float nw, nx, ny, nz;
    qmulf(st.qw, st.qx, st.qy, st.qz, s.Pw, s.Px, s.Py, s.Pz, nw, nx, ny, nz);
    float inv = 1.0f / sqrtf(nw*nw + nx*nx + ny*ny + nz*nz);
    r.qw = nw*inv; r.qx = nx*inv; r.qy = ny*inv; r.qz = nz*inv;
    return r;
}

__device__ __forceinline__ Sum loadSum(const float* __restrict__ p, int c) {
    const float* sp = p + (size_t)c*12;
    float4 a0 = ((const float4*)sp)[0];
    float4 a1 = ((const float4*)sp)[1];
    float4 a2 = ((const float4*)sp)[2];
    Sum s;
    s.Pw = a0.x; s.Px = a0.y; s.Py = a0.z; s.Pz = a0.w;
    s.T = a1.x; s.S = a1.y; s.Ux = a1.z; s.Uy = a1.w;
    s.Uz = a2.x; s.Wx = a2.y; s.Wy = a2.z; s.Wz = a2.w;
    return s;
}

__device__ __forceinline__ void storeSum(float* __restrict__ sp, const Sum& s) {
    ((float4*)sp)[0] = make_float4(s.Pw, s.Px, s.Py, s.Pz);
    ((float4*)sp)[1] = make_float4(s.T, s.S, s.Ux, s.Uy);
    ((float4*)sp)[2] = make_float4(s.Uz, s.Wx, s.Wy, s.Wz);
}

// ---- Kernel 0: pack weights into contiguous 64B/hidden-unit records ----
__global__ void repack_kernel(const float* __restrict__ Wenc, const float* __restrict__ benc,
                              const float* __restrict__ Wdec, float* __restrict__ wp) {
    int j = threadIdx.x;
    float* p = wp + j*16;
    p[0] = Wenc[0*NH+j]; p[1] = Wenc[1*NH+j]; p[2] = Wenc[2*NH+j];
    p[3] = Wenc[3*NH+j]; p[4] = Wenc[4*NH+j]; p[5] = Wenc[5*NH+j];
    p[6] = benc[j];
    p[7]  = Wdec[j*6+0]; p[8]  = Wdec[j*6+1]; p[9]  = Wdec[j*6+2];
    p[10] = Wdec[j*6+3]; p[11] = Wdec[j*6+4]; p[12] = Wdec[j*6+5];
    p[13] = 0.0f; p[14] = 0.0f; p[15] = 0.0f;
}

__device__ __forceinline__ f32x2 splat2(float v) { f32x2 r; r[0] = v; r[1] = v; return r; }

// ---- Kernel 1: MLP + record pack + per-chunk summaries.
// 128 rows/block, 2 rows per lane packed into <2 x float> vector ops so the
// backend emits v_pk_fma_f32 (VOP3P, 2 FMAs/inst); weights stay wave-uniform
// SGPR (op_sel broadcast). Only exp/rcp remain scalar per row.
__global__ __launch_bounds__(256)
void mlp_summ_kernel(const float* __restrict__ acc, const float* __restrict__ gyro,
                     const float* __restrict__ dtp, const float* __restrict__ wp,
                     const float* __restrict__ bdec,
                     float* __restrict__ out, float* __restrict__ rec,
                     float* __restrict__ summ) {
    __shared__ float part[4][128][8];               // 16 KB
    int t = threadIdx.x;
    int lane = t & 63;
    int wv = __builtin_amdgcn_readfirstlane(t >> 6);
    int base = blockIdx.x * 128;
    int n0 = base + lane;
    int n1 = base + 64 + lane;
    f32x2 AX, AY, AZ, GX2, GY2, GZ2;
    AX[0] = acc[n0*3+0];  AX[1] = acc[n1*3+0];
    AY[0] = acc[n0*3+1];  AY[1] = acc[n1*3+1];
    AZ[0] = acc[n0*3+2];  AZ[1] = acc[n1*3+2];
    GX2[0] = gyro[n0*3+0]; GX2[1] = gyro[n1*3+0];
    GY2[0] = gyro[n0*3+1]; GY2[1] = gyro[n1*3+1];
    GZ2[0] = gyro[n0*3+2]; GZ2[1] = gyro[n1*3+2];
    f32x2 C0 = splat2(0.f), C1 = splat2(0.f), C2 = splat2(0.f);
    f32x2 C3 = splat2(0.f), C4 = splat2(0.f), C5 = splat2(0.f);
    const f32x2 GK1 = splat2(-1.5957691216057308f);
    const f32x2 GK2 = splat2(-0.0713548162726009f);
    const f32x16* wbase = (const f32x16*)(wp) + wv*64;
    #pragma unroll 8
    for (int jj = 0; jj < 64; jj++) {
        f32x16 w = wbase[jj];                       // one s_load_dwordx16
        // encoder: packed FMAs over both rows
        f32x2 h = splat2(w[6]);
        h += splat2(w[0])*AX;  h += splat2(w[1])*AY;  h += splat2(w[2])*AZ;
        h += splat2(w[3])*GX2; h += splat2(w[4])*GY2; h += splat2(w[5])*GZ2;
        // gelu polynomial packed; exp/rcp scalar (no packed transcendentals)
        f32x2 h2 = h*h;
        f32x2 u2n = h*(GK1 + GK2*h2);
        f32x2 g;
        g[0] = __fdividef(h[0], 1.0f + __expf(u2n[0]));
        g[1] = __fdividef(h[1], 1.0f + __expf(u2n[1]));
        // decoder: packed FMAs
        C0 += g*splat2(w[7]);  C1 += g*splat2(w[8]);  C2 += g*splat2(w[9]);
        C3 += g*splat2(w[10]); C4 += g*splat2(w[11]); C5 += g*splat2(w[12]);
    }
    {
        float* pa = part[wv][lane];
        *(float4*)pa     = make_float4(C0[0], C1[0], C2[0], C3[0]);
        *(float2*)(pa+4) = make_float2(C4[0], C5[0]);
        float* pb = part[wv][64 + lane];
        *(float4*)pb     = make_float4(C0[1], C1[1], C2[1], C3[1]);
        *(float2*)(pb+4) = make_float2(C4[1], C5[1]);
    }
    __syncthreads();

    int rl = t & 127;                               // row-local 0..127
    int task = t >> 7;                              // 0: rec+summ, 1: out
    int rn = base + rl;
    float4 A = *(const float4*)part[0][rl];
    float2 B = *(const float2*)(part[0][rl]+4);
    #pragma unroll
    for (int w = 1; w < 4; w++) {
        float4 A2 = *(const float4*)part[w][rl];
        float2 B2 = *(const float2*)(part[w][rl]+4);
        A.x += A2.x; A.y += A2.y; A.z += A2.z; A.w += A2.w;
        B.x += B2.x; B.y += B2.y;
    }
    float e0 = A.x + bdec[0], e1 = A.y + bdec[1], e2 = A.z + bdec[2];
    float e3 = A.w + bdec[3], e4 = B.x + bdec[4], e5 = B.y + bdec[5];

    if (task == 1) {
        float* ob = out + (size_t)rn*16;
        *(float2*)(ob+10) = make_float2(e0, e1);
        *(float4*)(ob+12) = make_float4(e2, e3, e4, e5);
    } else {
        float dtv = dtp[rn];
        float cax = e0 + acc[rn*3+0], cay = e1 + acc[rn*3+1], caz = e2 + acc[rn*3+2];
        float cgx = e3 + gyro[rn*3+0], cgy = e4 + gyro[rn*3+1], cgz = e5 + gyro[rn*3+2];
        int ci = rn >> 2, ii = rn & 3;              // CL = 4
        float* rp = rec + (size_t)(ii*NCHUNK + ci)*8;
        *(float4*)rp     = make_float4(cax, cay, caz, cgx);
        *(float4*)(rp+4) = make_float4(cgy, cgz, dtv, 0.0f);

        Sum s;
        float hdt2 = 0.5f*dtv*dtv;
        qexpw(cgx*dtv, cgy*dtv, cgz*dtv, s.Pw, s.Px, s.Py, s.Pz);
        s.T = dtv; s.S = hdt2;
        s.Ux = cax*dtv;  s.Uy = cay*dtv;  s.Uz = caz*dtv;
        s.Wx = cax*hdt2; s.Wy = cay*hdt2; s.Wz = caz*hdt2;
        Sum nb = shflDownSum(s, 1);
        s = compose(s, nb);                         // valid at even lanes
        nb = shflDownSum(s, 2);
        s = compose(s, nb);                         // valid at lane%4==0
        if ((rl & 3) == 0) storeSum(summ + (size_t)(rn >> 2)*12, s);
    }
}

// ---- Kernel 2: in-block inclusive scan (one thread per chunk, 8 LDS rounds) ----
__global__ __launch_bounds__(256)
void scan1(const float* __restrict__ summ, float* __restrict__ pref,
           float* __restrict__ bsum) {
    __shared__ float lds[256*13];                   // stride 13: conflict-free
    int t = threadIdx.x;
    int c = blockIdx.x * 256 + t;
    Sum agg = loadSum(summ, c);
    float* mine = lds + t*13;
    mine[0]=agg.Pw; mine[1]=agg.Px; mine[2]=agg.Py; mine[3]=agg.Pz;
    mine[4]=agg.T;  mine[5]=agg.S;  mine[6]=agg.Ux; mine[7]=agg.Uy;
    mine[8]=agg.Uz; mine[9]=agg.Wx; mine[10]=agg.Wy; mine[11]=agg.Wz;
    __syncthreads();
    for (int d = 1; d < 256; d <<= 1) {
        Sum left;
        bool have = (t >= d);
        if (have) {
            const float* lp = lds + (t-d)*13;
            left.Pw=lp[0]; left.Px=lp[1]; left.Py=lp[2]; left.Pz=lp[3];
            left.T=lp[4];  left.S=lp[5];  left.Ux=lp[6]; left.Uy=lp[7];
            left.Uz=lp[8]; left.Wx=lp[9]; left.Wy=lp[10]; left.Wz=lp[11];
        }
        __syncthreads();
        if (have) {
            agg = compose(left, agg);
            mine[0]=agg.Pw; mine[1]=agg.Px; mine[2]=agg.Py; mine[3]=agg.Pz;
            mine[4]=agg.T;  mine[5]=agg.S;  mine[6]=agg.Ux; mine[7]=agg.Uy;
            mine[8]=agg.Uz; mine[9]=agg.Wx; mine[10]=agg.Wy; mine[11]=agg.Wz;
        }
        __syncthreads();
    }
    storeSum(pref + (size_t)c*12, agg);
    if (t == 255) storeSum(bsum + (size_t)blockIdx.x*12, agg);
}

// ---- Kernel 3: phaseC with inlined block-state combine.
__global__ __launch_bounds__(256)
void phaseC(const float* __restrict__ rec, const float* __restrict__ pref,
            const float* __restrict__ bsum,
            const float* __restrict__ init_pos, const float* __restrict__ init_vel,
            const float* __restrict__ init_rot, float* __restrict__ out) {
    __shared__ float bst[12];
    int t = threadIdx.x;
    int c = blockIdx.x * 256 + t;
    if (t == 0) {
        int b = blockIdx.x / BPB;
        int k0 = blockIdx.x % BPB;
        State st;
        st.px = init_pos[b*3+0]; st.py = init_pos[b*3+1]; st.pz = init_pos[b*3+2];
        st.vx = init_vel[b*3+0]; st.vy = init_vel[b*3+1]; st.vz = init_vel[b*3+2];
        st.qw = init_rot[b*4+0]; st.qx = init_rot[b*4+1]; st.qy = init_rot[b*4+2]; st.qz = init_rot[b*4+3];
        for (int k = 0; k < k0; k++)
            st = applySum(st, loadSum(bsum, b*BPB + k));
        bst[0]=st.px; bst[1]=st.py; bst[2]=st.pz; bst[3]=st.vx; bst[4]=st.vy;
        bst[5]=st.vz; bst[6]=st.qw; bst[7]=st.qx; bst[8]=st.qy; bst[9]=st.qz;
    }
    __syncthreads();
    State st;
    st.px = bst[0]; st.py = bst[1]; st.pz = bst[2];
    st.vx = bst[3]; st.vy = bst[4]; st.vz = bst[5];
    st.qw = bst[6]; st.qx = bst[7]; st.qy = bst[8]; st.qz = bst[9];
    if (t > 0) st = applySum(st, loadSum(pref, c-1));
    float px = st.px, py = st.py, pz = st.pz;
    float vx = st.vx, vy = st.vy, vz = st.vz;
    float qw = st.qw, qx = st.qx, qy = st.qy, qz = st.qz;
    const float4* r = (const float4*)rec;
    float* obase = out + (size_t)c*CL*16;
    #pragma unroll
    for (int i = 0; i < CL; i++) {
        float4 r0 = r[(size_t)(i*NCHUNK + c)*2];
        float4 r1 = r[(size_t)(i*NCHUNK + c)*2 + 1];
        float dtv = r1.z;
        float awx, awy, awz;
        qrotate(qw, qx, qy, qz, r0.x, r0.y, r0.z, awx, awy, awz);
        awz += GZ;
        float hdt2 = 0.5f*dtv*dtv;
        px += vx*dtv + awx*hdt2;
        py += vy*dtv + awy*hdt2;
        pz += vz*dtv + awz*hdt2;
        vx += awx*dtv; vy += awy*dtv; vz += awz*dtv;
        float ew, ex, ey, ez, nw, nx, ny, nz;
        qexpw(r0.w*dtv, r1.x*dtv, r1.y*dtv, ew, ex, ey, ez);
        qmulf(qw, qx, qy, qz, ew, ex, ey, ez, nw, nx, ny, nz);
        float inv = 1.0f / sqrtf(nw*nw + nx*nx + ny*ny + nz*nz);
        qw = nw*inv; qx = nx*inv; qy = ny*inv; qz = nz*inv;
        float* ob = obase + (size_t)i*16;
        *(float4*)(ob+0) = make_float4(px, py, pz, vx);
        *(float4*)(ob+4) = make_float4(vy, vz, qw, qx);
        *(float2*)(ob+8) = make_float2(qy, qz);
    }
}

extern "C" void kernel_launch(void* const* d_in, const int* in_sizes, int n_in,
                              void* d_out, int out_size, void* d_ws, size_t ws_size,
                              hipStream_t stream) {
    const float* acc      = (const float*)d_in[0];
    const float* gyro     = (const float*)d_in[1];
    const float* dt       = (const float*)d_in[2];
    const float* init_pos = (const float*)d_in[3];
    const float* init_vel = (const float*)d_in[4];
    const float* init_rot = (const float*)d_in[5];
    const float* Wenc     = (const float*)d_in[6];
    const float* benc     = (const float*)d_in[7];
    const float* Wdec     = (const float*)d_in[8];
    const float* bdec     = (const float*)d_in[9];
    float* out = (float*)d_out;
    float* ws  = (float*)d_ws;
    float* rec    = ws + REC_OFF;
    float* summ   = ws + SUMM_OFF;
    float* pref   = ws + PREF_OFF;
    float* wp     = ws + WPACK_OFF;
    float* bsum   = ws + BSUM_OFF;

    repack_kernel<<<1, NH, 0, stream>>>(Wenc, benc, Wdec, wp);
    mlp_summ_kernel<<<NROW/128, 256, 0, stream>>>(acc, gyro, dt, wp, bdec, out, rec, summ);
    scan1<<<SBLK, 256, 0, stream>>>(summ, pref, bsum);
    phaseC<<<SBLK, 256, 0, stream>>>(rec, pref, bsum, init_pos, init_vel, init_rot, out);
}